// Round 9
// baseline (6708.608 us; speedup 1.0000x reference)
//
#include <hip/hip_runtime.h>
#include <math.h>

#define BB 8
#define TT 256
#define HH 768
#define NL 12
#define NH_ 12
#define DH_ 64
#define FF_ 3072
#define LH_ 256
#define KK_ 9

typedef unsigned short u16;
typedef unsigned int u32;
typedef __attribute__((ext_vector_type(8))) short bf16x8;
typedef __attribute__((ext_vector_type(4))) float f32x4;

static __device__ __forceinline__ float sigmf(float x) { return 1.0f / (1.0f + expf(-x)); }

static __device__ __forceinline__ u16 f2bf(float f) {
    u32 u = __float_as_uint(f);
    u += 0x7fffu + ((u >> 16) & 1u);
    return (u16)(u >> 16);
}
static __device__ __forceinline__ float bf2f(u16 v) {
    return __uint_as_float(((u32)v) << 16);
}

#define GLL16(gp, lp) __builtin_amdgcn_global_load_lds( \
    (const __attribute__((address_space(1))) void*)(gp), \
    (__attribute__((address_space(3))) void*)(lp), 16, 0, 0)

// ---------------- block reduce ----------------
static __device__ __forceinline__ float block_sum(float v, float* red) {
    int tid = threadIdx.x;
#pragma unroll
    for (int o = 32; o > 0; o >>= 1) v += __shfl_xor(v, o);
    if ((tid & 63) == 0) red[tid >> 6] = v;
    __syncthreads();
    return red[0] + red[1] + red[2] + red[3];
}

// ---------------- embedding + LN ----------------
__global__ __launch_bounds__(256) void embed_ln_kernel(
    const int* __restrict__ ids, const float* __restrict__ we, const float* __restrict__ pe,
    const float* __restrict__ te, const float* __restrict__ g, const float* __restrict__ b,
    float* __restrict__ out, u16* __restrict__ outb) {
    int row = blockIdx.x;
    int t = row % TT;
    int id = ids[row];
    __shared__ float xr[HH];
    __shared__ float reda[8], redb[8];
    int tid = threadIdx.x;
    float s = 0.f;
    for (int h = tid; h < HH; h += 256) {
        float v = we[(size_t)id * HH + h] + pe[(size_t)t * HH + h] + te[h];
        xr[h] = v; s += v;
    }
    float mean = block_sum(s, reda) * (1.0f / HH);
    float vs = 0.f;
    for (int h = tid; h < HH; h += 256) { float d = xr[h] - mean; vs += d * d; }
    float var = block_sum(vs, redb) * (1.0f / HH);
    float rstd = rsqrtf(var + 1e-12f);
    for (int h = tid; h < HH; h += 256) {
        float v = (xr[h] - mean) * rstd * g[h] + b[h];
        out[(size_t)row * HH + h] = v;
        outb[(size_t)row * HH + h] = f2bf(v);
    }
}

// ---------------- LN(a + f) -> fp32 + bf16 ----------------
__global__ __launch_bounds__(256) void ln_residual_kernel(
    const float* __restrict__ a, const float* __restrict__ f,
    const float* __restrict__ g, const float* __restrict__ b,
    float* __restrict__ out, u16* __restrict__ outb) {
    int row = blockIdx.x;
    __shared__ float xr[HH];
    __shared__ float reda[8], redb[8];
    int tid = threadIdx.x;
    float s = 0.f;
    for (int h = tid; h < HH; h += 256) {
        float v = a[(size_t)row * HH + h] + f[(size_t)row * HH + h];
        xr[h] = v; s += v;
    }
    float mean = block_sum(s, reda) * (1.0f / HH);
    float vs = 0.f;
    for (int h = tid; h < HH; h += 256) { float d = xr[h] - mean; vs += d * d; }
    float var = block_sum(vs, redb) * (1.0f / HH);
    float rstd = rsqrtf(var + 1e-12f);
    for (int h = tid; h < HH; h += 256) {
        float v = (xr[h] - mean) * rstd * g[h] + b[h];
        out[(size_t)row * HH + h] = v;
        outb[(size_t)row * HH + h] = f2bf(v);
    }
}

// ---------------- per-layer weight transpose+convert: wbuf = bf16 [N][K] ----------------
__global__ __launch_bounds__(256) void conv_layer_w_kernel(
    const float* __restrict__ Wq, const float* __restrict__ Wk,
    const float* __restrict__ Wv, const float* __restrict__ Wo,
    const float* __restrict__ Wf1, const float* __restrict__ Wf2,
    u16* __restrict__ wbuf) {
    __shared__ float tile[32][33];
    int bid = blockIdx.x;
    const float* src; u16* dst; int R, C, bx, by;
    if (bid < 2304) {
        int m = bid / 576, t = bid % 576;
        src = (m == 0 ? Wq : m == 1 ? Wk : m == 2 ? Wv : Wo);
        dst = wbuf + (size_t)m * 589824;
        R = 768; C = 768; bx = t % 24; by = t / 24;
    } else if (bid < 4608) {
        int t = bid - 2304;
        src = Wf1; dst = wbuf + 2359296; R = 768; C = 3072;
        bx = t % 96; by = t / 96;
    } else {
        int t = bid - 4608;
        src = Wf2; dst = wbuf + 4718592; R = 3072; C = 768;
        bx = t % 24; by = t / 24;
    }
    int tx = threadIdx.x & 31, ty = threadIdx.x >> 5;
#pragma unroll
    for (int i = 0; i < 32; i += 8)
        tile[ty + i][tx] = src[(size_t)(by * 32 + ty + i) * C + bx * 32 + tx];
    __syncthreads();
#pragma unroll
    for (int i = 0; i < 32; i += 8)
        dst[(size_t)(bx * 32 + ty + i) * R + by * 32 + tx] = f2bf(tile[tx][ty + i]);
}

// ---------------- merged prologue: pack w_hh frags + convert w_ih (both dirs) ----------------
// bid<256: wfrag pack; bid<1024: w_ih_f convert; else w_ih_b convert.
__global__ __launch_bounds__(256) void prep_kernel(
    const float* __restrict__ whf, const float* __restrict__ whb,
    const float* __restrict__ wif, const float* __restrict__ wib,
    u16* __restrict__ wfrag, u16* __restrict__ wihT) {
    int bid = blockIdx.x;
    int tid = threadIdx.x;
    if (bid < 256) {
        int idx = bid * 256 + tid;   // 65536
        int dir = idx >> 15;
        int rem = idx & 32767;
        int mt = rem >> 9;
        int kt = (rem >> 6) & 7;
        int lane = rem & 63;
        const float* W = dir ? whb : whf;
        int row = mt * 16 + (lane & 15);
        int k = kt * 32 + (lane >> 4) * 8;
        const float* src = W + (size_t)row * LH_ + k;
        u16 o[8];
#pragma unroll
        for (int j = 0; j < 8; ++j) o[j] = f2bf(src[j]);
        uint4 pk;
        pk.x = (u32)o[0] | ((u32)o[1] << 16);
        pk.y = (u32)o[2] | ((u32)o[3] << 16);
        pk.z = (u32)o[4] | ((u32)o[5] << 16);
        pk.w = (u32)o[6] | ((u32)o[7] << 16);
        *(uint4*)&wfrag[(size_t)idx * 8] = pk;
    } else {
        int which = (bid < 1024) ? 0 : 1;
        const float* src = which ? wib : wif;
        u16* dst = wihT + (size_t)which * 786432;
        int i = (bid - (which ? 1024 : 256)) * 256 + tid;   // < 196608
        float4 v = *(const float4*)&src[(size_t)i * 4];
        uint2 o;
        o.x = (u32)f2bf(v.x) | ((u32)f2bf(v.y) << 16);
        o.y = (u32)f2bf(v.z) | ((u32)f2bf(v.w) << 16);
        *(uint2*)&dst[(size_t)i * 4] = o;
    }
}

// ---------------- GEMM v2: swizzled LDS + 2-phase double buffer ----------------
template <int BROWS>
__device__ __forceinline__ void stage_rows(
    const u16* __restrict__ S, int r0, int K, int k0, u16 (*lds)[64], int w, int lane) {
    int srow = lane >> 3;
    int sgrp = ((lane & 7) ^ srow) * 8;
#pragma unroll
    for (int i = 0; i < BROWS / 32; ++i) {
        int c = w * (BROWS / 32) + i;
        GLL16(S + (size_t)(r0 + 8 * c + srow) * K + k0 + sgrp, &lds[8 * c][0]);
    }
}

template <int BN, bool GELU, bool OUTBF>
__global__ __launch_bounds__(256) void gemm2_kernel(
    const u16* __restrict__ A, const u16* __restrict__ BT,
    const float* __restrict__ b0, const float* __restrict__ b1, const float* __restrict__ b2,
    int seg, float* __restrict__ C, u16* __restrict__ Cbf, int M, int N, int K) {
    __shared__ u16 Als[2][128][64];
    __shared__ u16 Bls[2][BN][64];
    int tid = threadIdx.x, lane = tid & 63, w = tid >> 6;
    int m0 = blockIdx.y * 128, n0 = blockIdx.x * BN;
    int wr = w >> 1, wc = w & 1;
    int l15 = lane & 15, q = lane >> 4;
    constexpr int NJ = BN / 32;

    f32x4 acc[4][NJ];
#pragma unroll
    for (int mi = 0; mi < 4; ++mi)
#pragma unroll
        for (int nj = 0; nj < NJ; ++nj) acc[mi][nj] = (f32x4){0.f, 0.f, 0.f, 0.f};

    stage_rows<128>(A, m0, K, 0, Als[0], w, lane);
    stage_rows<BN>(BT, n0, K, 0, Bls[0], w, lane);
    __syncthreads();
    int KT = K >> 6, cur = 0;
    for (int kt = 0; kt < KT; ++kt) {
        if (kt + 1 < KT) {
            stage_rows<128>(A, m0, K, (kt + 1) << 6, Als[cur ^ 1], w, lane);
            stage_rows<BN>(BT, n0, K, (kt + 1) << 6, Bls[cur ^ 1], w, lane);
        }
#pragma unroll
        for (int ks = 0; ks < 2; ++ks) {
            int g8 = (((ks * 4 + q) ^ (l15 & 7)) * 8);
            bf16x8 bfr[NJ];
#pragma unroll
            for (int nj = 0; nj < NJ; ++nj)
                bfr[nj] = *(const bf16x8*)&Bls[cur][wc * (BN / 2) + nj * 16 + l15][g8];
#pragma unroll
            for (int mi = 0; mi < 4; ++mi) {
                bf16x8 a = *(const bf16x8*)&Als[cur][wr * 64 + mi * 16 + l15][g8];
#pragma unroll
                for (int nj = 0; nj < NJ; ++nj)
                    acc[mi][nj] = __builtin_amdgcn_mfma_f32_16x16x32_bf16(a, bfr[nj], acc[mi][nj], 0, 0, 0);
            }
        }
        __syncthreads();
        cur ^= 1;
    }

    int rbase = m0 + wr * 64 + q * 4;
    int cbase = n0 + wc * (BN / 2) + l15;
#pragma unroll
    for (int mi = 0; mi < 4; ++mi) {
#pragma unroll
        for (int nj = 0; nj < NJ; ++nj) {
            int col = cbase + nj * 16;
            int cc = col;
            const float* bp;
            if (cc < seg) bp = b0;
            else if (cc < 2 * seg) { bp = b1; cc -= seg; }
            else { bp = b2; cc -= 2 * seg; }
            float bias = bp[cc];
#pragma unroll
            for (int j = 0; j < 4; ++j) {
                int row = rbase + mi * 16 + j;
                float v = acc[mi][nj][j] + bias;
                if (GELU) v = 0.5f * v * (1.0f + erff(v * 0.70710678118654752f));
                if (OUTBF) Cbf[(size_t)row * N + col] = f2bf(v);
                else       C[(size_t)row * N + col] = v;
            }
        }
    }
}

// ---------------- attention v2: pair-lane split, no spill ----------------
__global__ __launch_bounds__(256) void attention_kernel(
    const float* __restrict__ qkv, const int* __restrict__ mask, u16* __restrict__ ctxb) {
    int bid = blockIdx.x;
    int half = bid & 1;
    int bh = bid >> 1;
    int b = bh / NH_, h = bh % NH_;
    int tid = threadIdx.x;
    int q_i = half * 128 + (tid >> 1);
    int dh = tid & 1;
    const float* qp = qkv + (size_t)(b * TT + q_i) * 2304 + h * DH_ + dh * 32;
    float qv[32];
#pragma unroll
    for (int d = 0; d < 8; ++d) {
        float4 v = *(const float4*)(qp + 4 * d);
        qv[4 * d] = v.x; qv[4 * d + 1] = v.y; qv[4 * d + 2] = v.z; qv[4 * d + 3] = v.w;
    }
    const float* kbase = qkv + (size_t)b * TT * 2304 + 768 + h * DH_ + dh * 32;
    const float* vbase = qkv + (size_t)b * TT * 2304 + 1536 + h * DH_ + dh * 32;
    __shared__ float bias_s[TT];
    for (int i = tid; i < TT; i += 256)
        bias_s[i] = (1.0f - (float)mask[b * TT + i]) * -10000.0f;
    __syncthreads();
    float acc[32] = {};
    float l = 0.f;
    for (int kk = 0; kk < TT; ++kk) {
        const float4* kp = (const float4*)(kbase + (size_t)kk * 2304);
        float4 s4 = {0.f, 0.f, 0.f, 0.f};
#pragma unroll
        for (int d = 0; d < 8; ++d) {
            float4 k4 = kp[d];
            s4.x += qv[4 * d] * k4.x;
            s4.y += qv[4 * d + 1] * k4.y;
            s4.z += qv[4 * d + 2] * k4.z;
            s4.w += qv[4 * d + 3] * k4.w;
        }
        float part = (s4.x + s4.y) + (s4.z + s4.w);
        float s = part + __shfl_xor(part, 1);
        s = s * 0.125f + bias_s[kk];
        float p = expf(s);
        l += p;
        const float4* vp = (const float4*)(vbase + (size_t)kk * 2304);
#pragma unroll
        for (int d = 0; d < 8; ++d) {
            float4 v4 = vp[d];
            acc[4 * d] += p * v4.x;
            acc[4 * d + 1] += p * v4.y;
            acc[4 * d + 2] += p * v4.z;
            acc[4 * d + 3] += p * v4.w;
        }
    }
    float inv = 1.0f / l;
    size_t base = (size_t)(b * TT + q_i) * HH + h * DH_ + dh * 32;
#pragma unroll
    for (int d = 0; d < 16; ++d) {
        u32 pk = (u32)f2bf(acc[2 * d] * inv) | ((u32)f2bf(acc[2 * d + 1] * inv) << 16);
        *(u32*)&ctxb[base + 2 * d] = pk;
    }
}

// ---------------- LSTM v9: weights AGPR-pinned (kt0-4), LDS (kt5-6), streamed (kt7) ----------------
// 2 blocks (dir), 512 threads (8 waves, 2/SIMD -> 256 reg budget). AGPR file
// holds 160 regs of W ("a" constraint), VGPR side ~90 -> fits.
__global__ __launch_bounds__(512, 2) void lstm9_kernel(
    const float* __restrict__ xg, const u16* __restrict__ wfrag,
    const float* __restrict__ bhh_f, const float* __restrict__ bhh_b,
    float* __restrict__ hf, float* __restrict__ hb) {
    int dir = blockIdx.x;
    const u16* wf = wfrag + (size_t)dir * 262144;
    const float* bhh = dir ? bhh_b : bhh_f;
    float* hout = dir ? hb : hf;
    int tid = threadIdx.x, lane = tid & 63, wid = tid >> 6;   // wid 0..7
    __shared__ u16 wlds[2][64][512];      // kt=5,6 fragments, 128 KB
    __shared__ u16 h_bf[16][264];         // 8.25 KB
    __shared__ u16 g_bf[1024][10];        // 20 KB
    for (int i = tid; i < 16 * 264; i += 512) ((u16*)h_bf)[i] = 0;
#pragma unroll
    for (int kk = 0; kk < 2; ++kk)
#pragma unroll
        for (int i = 0; i < 8; ++i) {
            int mt = wid * 8 + i;
            GLL16(wf + ((size_t)(mt * 8 + 5 + kk)) * 512 + (size_t)lane * 8, &wlds[kk][mt][0]);
        }
    int l15 = lane & 15, qq = lane >> 4;
    const u16* wbase = wf + ((size_t)(wid * 8) * 8) * 512 + (size_t)lane * 8;
    // AGPR-resident weights: kt 0..4 for the wave's 8 m-tiles (160 AGPRs)
    bf16x8 wreg[8][5];
#pragma unroll
    for (int m = 0; m < 8; ++m)
#pragma unroll
        for (int kt = 0; kt < 5; ++kt) {
            wreg[m][kt] = *(const bf16x8*)(wbase + (size_t)(m * 8 + kt) * 512);
            asm volatile("" : "+a"(wreg[m][kt]));   // pin into AGPR file
        }
    int j = tid & 255;
    int bq = (tid >> 8) * 4;
    float bi_ = bhh[j], bf_ = bhh[256 + j], bg_ = bhh[512 + j], bo_ = bhh[768 + j];
    float c_s[4] = {0.f, 0.f, 0.f, 0.f};
    __syncthreads();
    for (int step = 0; step < TT; ++step) {
        int t = dir ? (TT - 1 - step) : step;
        float xgi[4], xgf[4], xgg[4], xgo[4];
#pragma unroll
        for (int bi = 0; bi < 4; ++bi) {
            size_t xa = ((size_t)((bq + bi) * TT + t)) * 2048 + (size_t)dir * 1024;
            xgi[bi] = xg[xa + j];
            xgf[bi] = xg[xa + 256 + j];
            xgg[bi] = xg[xa + 512 + j];
            xgo[bi] = xg[xa + 768 + j];
        }
        f32x4 acc[8];
#pragma unroll
        for (int m = 0; m < 8; ++m) acc[m] = (f32x4){0.f, 0.f, 0.f, 0.f};
#pragma unroll
        for (int kt = 0; kt < 5; ++kt) {
            bf16x8 hfr = *(const bf16x8*)&h_bf[l15][kt * 32 + qq * 8];
#pragma unroll
            for (int m = 0; m < 8; ++m)
                acc[m] = __builtin_amdgcn_mfma_f32_16x16x32_bf16(wreg[m][kt], hfr, acc[m], 0, 0, 0);
        }
#pragma unroll
        for (int kk = 0; kk < 2; ++kk) {
            bf16x8 hfr = *(const bf16x8*)&h_bf[l15][(5 + kk) * 32 + qq * 8];
#pragma unroll
            for (int m = 0; m < 8; ++m) {
                bf16x8 ws = *(const bf16x8*)&wlds[kk][wid * 8 + m][lane * 8];
                acc[m] = __builtin_amdgcn_mfma_f32_16x16x32_bf16(ws, hfr, acc[m], 0, 0, 0);
            }
        }
        {
            bf16x8 hfr = *(const bf16x8*)&h_bf[l15][7 * 32 + qq * 8];
#pragma unroll
            for (int m = 0; m < 8; ++m) {
                bf16x8 ws = *(const bf16x8*)(wbase + (size_t)(m * 8 + 7) * 512);
                acc[m] = __builtin_amdgcn_mfma_f32_16x16x32_bf16(ws, hfr, acc[m], 0, 0, 0);
            }
        }
        if (l15 < 8) {
#pragma unroll
            for (int m = 0; m < 8; ++m) {
                int R = wid * 128 + m * 16 + qq * 4;
#pragma unroll
                for (int jj = 0; jj < 4; ++jj) g_bf[R + jj][l15] = f2bf(acc[m][jj]);
            }
        }
        __syncthreads();
#pragma unroll
        for (int bi = 0; bi < 4; ++bi) {
            int b = bq + bi;
            float gi = xgi[bi] + bi_ + bf2f(g_bf[j][b]);
            float gf = xgf[bi] + bf_ + bf2f(g_bf[256 + j][b]);
            float gg = xgg[bi] + bg_ + bf2f(g_bf[512 + j][b]);
            float go = xgo[bi] + bo_ + bf2f(g_bf[768 + j][b]);
            float cc = sigmf(gf) * c_s[bi] + sigmf(gi) * tanhf(gg);
            c_s[bi] = cc;
            float hh = sigmf(go) * tanhf(cc);
            h_bf[b][j] = f2bf(hh);
            hout[((size_t)(b * TT + t)) * LH_ + j] = hh;
        }
        __syncthreads();
    }
}

// ---------------- classifier ----------------
__global__ __launch_bounds__(256) void clf_kernel(
    const float* __restrict__ hf, const float* __restrict__ hb,
    const float* __restrict__ W, const float* __restrict__ bias, float* __restrict__ em) {
    int idx = blockIdx.x * blockDim.x + threadIdx.x;
    if (idx >= BB * TT * KK_) return;
    int row = idx / KK_, j = idx % KK_;
    float acc = bias[j];
    const float* hfp = hf + (size_t)row * LH_;
    const float* hbp = hb + (size_t)row * LH_;
    for (int kk = 0; kk < LH_; ++kk) acc += hfp[kk] * W[kk * KK_ + j];
    for (int kk = 0; kk < LH_; ++kk) acc += hbp[kk] * W[(LH_ + kk) * KK_ + j];
    em[idx] = acc;
}

// ---------------- CRF ----------------
__global__ __launch_bounds__(128) void crf_kernel(
    const float* __restrict__ em, const int* __restrict__ labels, const int* __restrict__ mask,
    const float* __restrict__ cstart, const float* __restrict__ cend,
    const float* __restrict__ ctrans, float* __restrict__ out) {
    __shared__ float alpha[BB][KK_], nxt[BB][KK_], trans[KK_ * KK_];
    __shared__ float score_s[BB], logZ_s[BB];
    int tid = threadIdx.x;
    if (tid < KK_ * KK_) trans[tid] = ctrans[tid];
    __syncthreads();
    int b = tid / KK_, j = tid % KK_;
    if (tid < BB * KK_) alpha[b][j] = cstart[j] + em[(size_t)b * TT * KK_ + j];
    __syncthreads();
    for (int t = 1; t < TT; ++t) {
        if (tid < BB * KK_) {
            float m = -1e30f;
            for (int i = 0; i < KK_; ++i) m = fmaxf(m, alpha[b][i] + trans[i * KK_ + j]);
            float s = 0.f;
            for (int i = 0; i < KK_; ++i) s += expf(alpha[b][i] + trans[i * KK_ + j] - m);
            float nv = m + logf(s) + em[((size_t)b * TT + t) * KK_ + j];
            nxt[b][j] = (mask[b * TT + t] > 0) ? nv : alpha[b][j];
        }
        __syncthreads();
        if (tid < BB * KK_) alpha[b][j] = nxt[b][j];
        __syncthreads();
    }
    if (tid < BB) {
        int bb = tid;
        int l0 = labels[bb * TT];
        float sc = cstart[l0] + em[(size_t)bb * TT * KK_ + l0];
        int prev = l0;
        for (int t = 1; t < TT; ++t) {
            int lt = labels[bb * TT + t];
            float mf = (float)mask[bb * TT + t];
            sc += (trans[prev * KK_ + lt] + em[((size_t)bb * TT + t) * KK_ + lt]) * mf;
            prev = lt;
        }
        int ends = 0;
        for (int t = 0; t < TT; ++t) ends += mask[bb * TT + t];
        ends -= 1;
        int last = labels[bb * TT + ends];
        sc += cend[last];
        score_s[bb] = sc;
        float m = -1e30f;
        for (int jj = 0; jj < KK_; ++jj) m = fmaxf(m, alpha[bb][jj] + cend[jj]);
        float s = 0.f;
        for (int jj = 0; jj < KK_; ++jj) s += expf(alpha[bb][jj] + cend[jj] - m);
        logZ_s[bb] = m + logf(s);
    }
    __syncthreads();
    if (tid == 0) {
        float acc = 0.f;
        for (int bb = 0; bb < BB; ++bb) acc += score_s[bb] - logZ_s[bb];
        out[0] = -acc / (float)BB;
    }
}

extern "C" void kernel_launch(void* const* d_in, const int* in_sizes, int n_in,
                              void* d_out, int out_size, void* d_ws, size_t ws_size,
                              hipStream_t stream) {
    const int* input_ids = (const int*)d_in[0];
    const int* attn_mask = (const int*)d_in[1];
    const int* labels    = (const int*)d_in[2];
    const float* word_emb = (const float*)d_in[3];
    const float* pos_emb  = (const float*)d_in[4];
    const float* type_emb = (const float*)d_in[5];
    const float* emb_ln_g = (const float*)d_in[6];
    const float* emb_ln_b = (const float*)d_in[7];
    const float* Wq = (const float*)d_in[8];
    const float* bq = (const float*)d_in[9];
    const float* Wk = (const float*)d_in[10];
    const float* bk = (const float*)d_in[11];
    const float* Wv = (const float*)d_in[12];
    const float* bv = (const float*)d_in[13];
    const float* Wo = (const float*)d_in[14];
    const float* bo = (const float*)d_in[15];
    const float* ln1_g = (const float*)d_in[16];
    const float* ln1_b = (const float*)d_in[17];
    const float* Wf1 = (const float*)d_in[18];
    const float* bf1 = (const float*)d_in[19];
    const float* Wf2 = (const float*)d_in[20];
    const float* bf2 = (const float*)d_in[21];
    const float* ln2_g = (const float*)d_in[22];
    const float* ln2_b = (const float*)d_in[23];
    const float* w_ih_f = (const float*)d_in[24];
    const float* w_hh_f = (const float*)d_in[25];
    const float* b_ih_f = (const float*)d_in[26];
    const float* b_hh_f = (const float*)d_in[27];
    const float* w_ih_b = (const float*)d_in[28];
    const float* w_hh_b = (const float*)d_in[29];
    const float* b_ih_b = (const float*)d_in[30];
    const float* b_hh_b = (const float*)d_in[31];
    const float* W_clf  = (const float*)d_in[32];
    const float* b_clf  = (const float*)d_in[33];
    const float* crf_start = (const float*)d_in[34];
    const float* crf_end   = (const float*)d_in[35];
    const float* crf_trans = (const float*)d_in[36];

    const size_t NTOK = (size_t)BB * TT;          // 2048
    const size_t SZ = NTOK * HH;                  // 1,572,864

    float* ws = (float*)d_ws;
    float* x    = ws;                              // SZ
    float* qkv  = x + SZ;                          // 2048*2304
    float* tmp  = qkv + NTOK * 2304;               // SZ
    float* ab   = tmp + SZ;                        // SZ
    float* xg   = ab + SZ;                         // 2048*2048
    u16* x_bf   = (u16*)(xg + NTOK * 2048);        // SZ u16
    u16* ab_bf  = x_bf + SZ;
    u16* ctx_bf = ab_bf + SZ;
    u16* big_bf = ctx_bf + SZ;                     // 2048*3072
    u16* wbuf   = big_bf + NTOK * (size_t)FF_;     // 7,077,888
    u16* wihT   = wbuf + 7077888;                  // 2048*768
    u16* wfrag  = wihT + 1572864;                  // 524,288
    float* hf = qkv;
    float* hb = qkv + 524288;
    float* em = qkv + 1048576;

    embed_ln_kernel<<<NTOK, 256, 0, stream>>>(input_ids, word_emb, pos_emb, type_emb,
                                              emb_ln_g, emb_ln_b, x, x_bf);

    prep_kernel<<<1792, 256, 0, stream>>>(w_hh_f, w_hh_b, w_ih_f, w_ih_b, wfrag, wihT);

    dim3 gQKV(2304 / 128, NTOK / 128);  // 18 x 16
    dim3 gH(HH / 64, NTOK / 128);       // 12 x 16
    dim3 gF1(FF_ / 128, NTOK / 128);    // 24 x 16
    dim3 gG(2048 / 128, NTOK / 128);    // 16 x 16

    for (int l = 0; l < NL; ++l) {
        conv_layer_w_kernel<<<6912, 256, 0, stream>>>(
            Wq + (size_t)l * HH * HH, Wk + (size_t)l * HH * HH,
            Wv + (size_t)l * HH * HH, Wo + (size_t)l * HH * HH,
            Wf1 + (size_t)l * HH * FF_, Wf2 + (size_t)l * FF_ * HH, wbuf);

        const float* bq_l = bq + (size_t)l * HH;
        const float* bk_l = bk + (size_t)l * HH;
        const float* bv_l = bv + (size_t)l * HH;
        const float* bo_l = bo + (size_t)l * HH;
        const float* g1 = ln1_g + (size_t)l * HH;
        const float* b1 = ln1_b + (size_t)l * HH;
        const float* bf1_l = bf1 + (size_t)l * FF_;
        const float* bf2_l = bf2 + (size_t)l * HH;
        const float* g2 = ln2_g + (size_t)l * HH;
        const float* b2 = ln2_b + (size_t)l * HH;

        gemm2_kernel<128, false, false><<<gQKV, 256, 0, stream>>>(
            x_bf, wbuf, bq_l, bk_l, bv_l, 768, qkv, nullptr, NTOK, 2304, HH);
        attention_kernel<<<BB * NH_ * 2, 256, 0, stream>>>(qkv, attn_mask, ctx_bf);
        gemm2_kernel<64, false, false><<<gH, 256, 0, stream>>>(
            ctx_bf, wbuf + 1769472, bo_l, bo_l, bo_l, 768, tmp, nullptr, NTOK, HH, HH);
        ln_residual_kernel<<<NTOK, 256, 0, stream>>>(x, tmp, g1, b1, ab, ab_bf);
        gemm2_kernel<128, true, true><<<gF1, 256, 0, stream>>>(
            ab_bf, wbuf + 2359296, bf1_l, bf1_l, bf1_l, FF_, nullptr, big_bf, NTOK, FF_, HH);
        gemm2_kernel<64, false, false><<<gH, 256, 0, stream>>>(
            big_bf, wbuf + 4718592, bf2_l, bf2_l, bf2_l, 768, tmp, nullptr, NTOK, HH, FF_);
        ln_residual_kernel<<<NTOK, 256, 0, stream>>>(ab, tmp, g2, b2, x, x_bf);
    }

    // fused LSTM input projections: xg[tok][dir*1024+g]
    gemm2_kernel<128, false, false><<<gG, 256, 0, stream>>>(
        x_bf, wihT, b_ih_f, b_ih_b, b_ih_b, 1024, xg, nullptr, NTOK, 2048, HH);

    lstm9_kernel<<<2, 512, 0, stream>>>(xg, wfrag, b_hh_f, b_hh_b, hf, hb);
    clf_kernel<<<(BB * TT * KK_ + 255) / 256, 256, 0, stream>>>(hf, hb, W_clf, b_clf, em);
    crf_kernel<<<1, 128, 0, stream>>>(em, labels, attn_mask, crf_start, crf_end, crf_trans,
                                      (float*)d_out);
}

// Round 10
// 6210.517 us; speedup vs baseline: 1.0802x; 1.0802x over previous
//
#include <hip/hip_runtime.h>
#include <math.h>

#define BB 8
#define TT 256
#define HH 768
#define NL 12
#define NH_ 12
#define DH_ 64
#define FF_ 3072
#define LH_ 256
#define KK_ 9

typedef unsigned short u16;
typedef unsigned int u32;
typedef __attribute__((ext_vector_type(8))) short bf16x8;
typedef __attribute__((ext_vector_type(4))) float f32x4;

static __device__ __forceinline__ float sigmf(float x) { return 1.0f / (1.0f + expf(-x)); }

static __device__ __forceinline__ u16 f2bf(float f) {
    u32 u = __float_as_uint(f);
    u += 0x7fffu + ((u >> 16) & 1u);
    return (u16)(u >> 16);
}
static __device__ __forceinline__ float bf2f(u16 v) {
    return __uint_as_float(((u32)v) << 16);
}

#define GLL16(gp, lp) __builtin_amdgcn_global_load_lds( \
    (const __attribute__((address_space(1))) void*)(gp), \
    (__attribute__((address_space(3))) void*)(lp), 16, 0, 0)

// ---------------- block reduce ----------------
static __device__ __forceinline__ float block_sum(float v, float* red) {
    int tid = threadIdx.x;
#pragma unroll
    for (int o = 32; o > 0; o >>= 1) v += __shfl_xor(v, o);
    if ((tid & 63) == 0) red[tid >> 6] = v;
    __syncthreads();
    return red[0] + red[1] + red[2] + red[3];
}

// ---------------- embedding + LN ----------------
__global__ __launch_bounds__(256) void embed_ln_kernel(
    const int* __restrict__ ids, const float* __restrict__ we, const float* __restrict__ pe,
    const float* __restrict__ te, const float* __restrict__ g, const float* __restrict__ b,
    float* __restrict__ out, u16* __restrict__ outb) {
    int row = blockIdx.x;
    int t = row % TT;
    int id = ids[row];
    __shared__ float xr[HH];
    __shared__ float reda[8], redb[8];
    int tid = threadIdx.x;
    float s = 0.f;
    for (int h = tid; h < HH; h += 256) {
        float v = we[(size_t)id * HH + h] + pe[(size_t)t * HH + h] + te[h];
        xr[h] = v; s += v;
    }
    float mean = block_sum(s, reda) * (1.0f / HH);
    float vs = 0.f;
    for (int h = tid; h < HH; h += 256) { float d = xr[h] - mean; vs += d * d; }
    float var = block_sum(vs, redb) * (1.0f / HH);
    float rstd = rsqrtf(var + 1e-12f);
    for (int h = tid; h < HH; h += 256) {
        float v = (xr[h] - mean) * rstd * g[h] + b[h];
        out[(size_t)row * HH + h] = v;
        outb[(size_t)row * HH + h] = f2bf(v);
    }
}

// ---------------- LN(a + f) -> fp32 + bf16 ----------------
__global__ __launch_bounds__(256) void ln_residual_kernel(
    const float* __restrict__ a, const float* __restrict__ f,
    const float* __restrict__ g, const float* __restrict__ b,
    float* __restrict__ out, u16* __restrict__ outb) {
    int row = blockIdx.x;
    __shared__ float xr[HH];
    __shared__ float reda[8], redb[8];
    int tid = threadIdx.x;
    float s = 0.f;
    for (int h = tid; h < HH; h += 256) {
        float v = a[(size_t)row * HH + h] + f[(size_t)row * HH + h];
        xr[h] = v; s += v;
    }
    float mean = block_sum(s, reda) * (1.0f / HH);
    float vs = 0.f;
    for (int h = tid; h < HH; h += 256) { float d = xr[h] - mean; vs += d * d; }
    float var = block_sum(vs, redb) * (1.0f / HH);
    float rstd = rsqrtf(var + 1e-12f);
    for (int h = tid; h < HH; h += 256) {
        float v = (xr[h] - mean) * rstd * g[h] + b[h];
        out[(size_t)row * HH + h] = v;
        outb[(size_t)row * HH + h] = f2bf(v);
    }
}

// ---------------- per-layer weight transpose+convert v2: 64x64 tiles ----------------
// dst[C][R] = bf16(src[R][C]); both read and write coalesced at 128B+.
__global__ __launch_bounds__(256) void conv_layer_w2_kernel(
    const float* __restrict__ Wq, const float* __restrict__ Wk,
    const float* __restrict__ Wv, const float* __restrict__ Wo,
    const float* __restrict__ Wf1, const float* __restrict__ Wf2,
    u16* __restrict__ wbuf) {
    __shared__ float tile[64][65];
    int bid = blockIdx.x;
    const float* src; u16* dst; int R, C, bx, by;
    if (bid < 576) {
        int m = bid / 144, t = bid % 144;
        src = (m == 0 ? Wq : m == 1 ? Wk : m == 2 ? Wv : Wo);
        dst = wbuf + (size_t)m * 589824;
        R = 768; C = 768; bx = t % 12; by = t / 12;
    } else if (bid < 1152) {
        int t = bid - 576;
        src = Wf1; dst = wbuf + 2359296; R = 768; C = 3072;
        bx = t % 48; by = t / 48;
    } else {
        int t = bid - 1152;
        src = Wf2; dst = wbuf + 4718592; R = 3072; C = 768;
        bx = t % 12; by = t / 12;
    }
    int tx = threadIdx.x & 15, ty = threadIdx.x >> 4;   // 16 x 16
#pragma unroll
    for (int p = 0; p < 4; ++p) {
        int row = p * 16 + ty;
        float4 v = *(const float4*)&src[(size_t)(by * 64 + row) * C + bx * 64 + tx * 4];
        tile[row][tx * 4 + 0] = v.x; tile[row][tx * 4 + 1] = v.y;
        tile[row][tx * 4 + 2] = v.z; tile[row][tx * 4 + 3] = v.w;
    }
    __syncthreads();
    int rr = (threadIdx.x & 31) * 2, cc0 = threadIdx.x >> 5;   // 8 cols/pass
#pragma unroll
    for (int p = 0; p < 8; ++p) {
        int cc = p * 8 + cc0;
        u32 pk = (u32)f2bf(tile[rr][cc]) | ((u32)f2bf(tile[rr + 1][cc]) << 16);
        *(u32*)&dst[(size_t)(bx * 64 + cc) * R + by * 64 + rr] = pk;
    }
}

// ---------------- merged prologue: pack w_hh frags + convert w_ih (both dirs) ----------------
__global__ __launch_bounds__(256) void prep_kernel(
    const float* __restrict__ whf, const float* __restrict__ whb,
    const float* __restrict__ wif, const float* __restrict__ wib,
    u16* __restrict__ wfrag, u16* __restrict__ wihT) {
    int bid = blockIdx.x;
    int tid = threadIdx.x;
    if (bid < 256) {
        int idx = bid * 256 + tid;   // 65536
        int dir = idx >> 15;
        int rem = idx & 32767;
        int mt = rem >> 9;
        int kt = (rem >> 6) & 7;
        int lane = rem & 63;
        const float* W = dir ? whb : whf;
        int row = mt * 16 + (lane & 15);
        int k = kt * 32 + (lane >> 4) * 8;
        const float* src = W + (size_t)row * LH_ + k;
        u16 o[8];
#pragma unroll
        for (int j = 0; j < 8; ++j) o[j] = f2bf(src[j]);
        uint4 pk;
        pk.x = (u32)o[0] | ((u32)o[1] << 16);
        pk.y = (u32)o[2] | ((u32)o[3] << 16);
        pk.z = (u32)o[4] | ((u32)o[5] << 16);
        pk.w = (u32)o[6] | ((u32)o[7] << 16);
        *(uint4*)&wfrag[(size_t)idx * 8] = pk;
    } else {
        int which = (bid < 1024) ? 0 : 1;
        const float* src = which ? wib : wif;
        u16* dst = wihT + (size_t)which * 786432;
        int i = (bid - (which ? 1024 : 256)) * 256 + tid;   // < 196608
        float4 v = *(const float4*)&src[(size_t)i * 4];
        uint2 o;
        o.x = (u32)f2bf(v.x) | ((u32)f2bf(v.y) << 16);
        o.y = (u32)f2bf(v.z) | ((u32)f2bf(v.w) << 16);
        *(uint2*)&dst[(size_t)i * 4] = o;
    }
}

// ---------------- GEMM v2: swizzled LDS + 2-phase double buffer ----------------
template <int BROWS>
__device__ __forceinline__ void stage_rows(
    const u16* __restrict__ S, int r0, int K, int k0, u16 (*lds)[64], int w, int lane) {
    int srow = lane >> 3;
    int sgrp = ((lane & 7) ^ srow) * 8;
#pragma unroll
    for (int i = 0; i < BROWS / 32; ++i) {
        int c = w * (BROWS / 32) + i;
        GLL16(S + (size_t)(r0 + 8 * c + srow) * K + k0 + sgrp, &lds[8 * c][0]);
    }
}

template <int BN, bool GELU, bool OUTBF>
__global__ __launch_bounds__(256) void gemm2_kernel(
    const u16* __restrict__ A, const u16* __restrict__ BT,
    const float* __restrict__ b0, const float* __restrict__ b1, const float* __restrict__ b2,
    int seg, float* __restrict__ C, u16* __restrict__ Cbf, int M, int N, int K) {
    __shared__ u16 Als[2][128][64];
    __shared__ u16 Bls[2][BN][64];
    int tid = threadIdx.x, lane = tid & 63, w = tid >> 6;
    int m0 = blockIdx.y * 128, n0 = blockIdx.x * BN;
    int wr = w >> 1, wc = w & 1;
    int l15 = lane & 15, q = lane >> 4;
    constexpr int NJ = BN / 32;

    f32x4 acc[4][NJ];
#pragma unroll
    for (int mi = 0; mi < 4; ++mi)
#pragma unroll
        for (int nj = 0; nj < NJ; ++nj) acc[mi][nj] = (f32x4){0.f, 0.f, 0.f, 0.f};

    stage_rows<128>(A, m0, K, 0, Als[0], w, lane);
    stage_rows<BN>(BT, n0, K, 0, Bls[0], w, lane);
    __syncthreads();
    int KT = K >> 6, cur = 0;
    for (int kt = 0; kt < KT; ++kt) {
        if (kt + 1 < KT) {
            stage_rows<128>(A, m0, K, (kt + 1) << 6, Als[cur ^ 1], w, lane);
            stage_rows<BN>(BT, n0, K, (kt + 1) << 6, Bls[cur ^ 1], w, lane);
        }
#pragma unroll
        for (int ks = 0; ks < 2; ++ks) {
            int g8 = (((ks * 4 + q) ^ (l15 & 7)) * 8);
            bf16x8 bfr[NJ];
#pragma unroll
            for (int nj = 0; nj < NJ; ++nj)
                bfr[nj] = *(const bf16x8*)&Bls[cur][wc * (BN / 2) + nj * 16 + l15][g8];
#pragma unroll
            for (int mi = 0; mi < 4; ++mi) {
                bf16x8 a = *(const bf16x8*)&Als[cur][wr * 64 + mi * 16 + l15][g8];
#pragma unroll
                for (int nj = 0; nj < NJ; ++nj)
                    acc[mi][nj] = __builtin_amdgcn_mfma_f32_16x16x32_bf16(a, bfr[nj], acc[mi][nj], 0, 0, 0);
            }
        }
        __syncthreads();
        cur ^= 1;
    }

    int rbase = m0 + wr * 64 + q * 4;
    int cbase = n0 + wc * (BN / 2) + l15;
#pragma unroll
    for (int mi = 0; mi < 4; ++mi) {
#pragma unroll
        for (int nj = 0; nj < NJ; ++nj) {
            int col = cbase + nj * 16;
            int cc = col;
            const float* bp;
            if (cc < seg) bp = b0;
            else if (cc < 2 * seg) { bp = b1; cc -= seg; }
            else { bp = b2; cc -= 2 * seg; }
            float bias = bp[cc];
#pragma unroll
            for (int j = 0; j < 4; ++j) {
                int row = rbase + mi * 16 + j;
                float v = acc[mi][nj][j] + bias;
                if (GELU) v = 0.5f * v * (1.0f + erff(v * 0.70710678118654752f));
                if (OUTBF) Cbf[(size_t)row * N + col] = f2bf(v);
                else       C[(size_t)row * N + col] = v;
            }
        }
    }
}

// ---------------- attention v2: pair-lane split, no spill ----------------
__global__ __launch_bounds__(256) void attention_kernel(
    const float* __restrict__ qkv, const int* __restrict__ mask, u16* __restrict__ ctxb) {
    int bid = blockIdx.x;
    int half = bid & 1;
    int bh = bid >> 1;
    int b = bh / NH_, h = bh % NH_;
    int tid = threadIdx.x;
    int q_i = half * 128 + (tid >> 1);
    int dh = tid & 1;
    const float* qp = qkv + (size_t)(b * TT + q_i) * 2304 + h * DH_ + dh * 32;
    float qv[32];
#pragma unroll
    for (int d = 0; d < 8; ++d) {
        float4 v = *(const float4*)(qp + 4 * d);
        qv[4 * d] = v.x; qv[4 * d + 1] = v.y; qv[4 * d + 2] = v.z; qv[4 * d + 3] = v.w;
    }
    const float* kbase = qkv + (size_t)b * TT * 2304 + 768 + h * DH_ + dh * 32;
    const float* vbase = qkv + (size_t)b * TT * 2304 + 1536 + h * DH_ + dh * 32;
    __shared__ float bias_s[TT];
    for (int i = tid; i < TT; i += 256)
        bias_s[i] = (1.0f - (float)mask[b * TT + i]) * -10000.0f;
    __syncthreads();
    float acc[32] = {};
    float l = 0.f;
    for (int kk = 0; kk < TT; ++kk) {
        const float4* kp = (const float4*)(kbase + (size_t)kk * 2304);
        float4 s4 = {0.f, 0.f, 0.f, 0.f};
#pragma unroll
        for (int d = 0; d < 8; ++d) {
            float4 k4 = kp[d];
            s4.x += qv[4 * d] * k4.x;
            s4.y += qv[4 * d + 1] * k4.y;
            s4.z += qv[4 * d + 2] * k4.z;
            s4.w += qv[4 * d + 3] * k4.w;
        }
        float part = (s4.x + s4.y) + (s4.z + s4.w);
        float s = part + __shfl_xor(part, 1);
        s = s * 0.125f + bias_s[kk];
        float p = expf(s);
        l += p;
        const float4* vp = (const float4*)(vbase + (size_t)kk * 2304);
#pragma unroll
        for (int d = 0; d < 8; ++d) {
            float4 v4 = vp[d];
            acc[4 * d] += p * v4.x;
            acc[4 * d + 1] += p * v4.y;
            acc[4 * d + 2] += p * v4.z;
            acc[4 * d + 3] += p * v4.w;
        }
    }
    float inv = 1.0f / l;
    size_t base = (size_t)(b * TT + q_i) * HH + h * DH_ + dh * 32;
#pragma unroll
    for (int d = 0; d < 16; ++d) {
        u32 pk = (u32)f2bf(acc[2 * d] * inv) | ((u32)f2bf(acc[2 * d + 1] * inv) << 16);
        *(u32*)&ctxb[base + 2 * d] = pk;
    }
}

// ---------------- LSTM v10: 16 waves, wreg[4][4]=64 VGPR/wave (256KB resident total) ----------------
// kt0-3 regs, kt4-5 LDS (128KB), kt6-7 streamed (128KB/step). 1024 thr, 4 waves/EU
// -> 128-reg cap, design fits (~113).
__global__ __launch_bounds__(1024, 4) void lstm10_kernel(
    const float* __restrict__ xg, const u16* __restrict__ wfrag,
    const float* __restrict__ bhh_f, const float* __restrict__ bhh_b,
    float* __restrict__ hf, float* __restrict__ hb) {
    int dir = blockIdx.x;
    const u16* wf = wfrag + (size_t)dir * 262144;
    const float* bhh = dir ? bhh_b : bhh_f;
    float* hout = dir ? hb : hf;
    int tid = threadIdx.x, lane = tid & 63, wid = tid >> 6;   // wid 0..15
    __shared__ u16 wlds[2][64][512];      // kt=4,5: 128 KB
    __shared__ u16 h_bf[16][264];         // 8.25 KB
    __shared__ u16 g_bf[1024][10];        // 20 KB
    for (int i = tid; i < 16 * 264; i += 1024) ((u16*)h_bf)[i] = 0;
#pragma unroll
    for (int kk = 0; kk < 2; ++kk)
#pragma unroll
        for (int i = 0; i < 4; ++i) {
            int mt = wid * 4 + i;
            GLL16(wf + ((size_t)(mt * 8 + 4 + kk)) * 512 + (size_t)lane * 8, &wlds[kk][mt][0]);
        }
    int l15 = lane & 15, qq = lane >> 4;
    const u16* wbase = wf + ((size_t)(wid * 4) * 8) * 512 + (size_t)lane * 8;
    bf16x8 wreg[4][4];
#pragma unroll
    for (int m = 0; m < 4; ++m)
#pragma unroll
        for (int kt = 0; kt < 4; ++kt) {
            wreg[m][kt] = *(const bf16x8*)(wbase + (size_t)(m * 8 + kt) * 512);
            asm volatile("" : "+v"(wreg[m][kt]));
        }
    int j = tid & 255;
    int bq = (tid >> 8) * 2;   // 2 batches per thread
    float bi_ = bhh[j], bf_ = bhh[256 + j], bg_ = bhh[512 + j], bo_ = bhh[768 + j];
    float c_s[2] = {0.f, 0.f};
    __syncthreads();
    for (int step = 0; step < TT; ++step) {
        int t = dir ? (TT - 1 - step) : step;
        float xgi[2], xgf[2], xgg[2], xgo[2];
#pragma unroll
        for (int bi = 0; bi < 2; ++bi) {
            size_t xa = ((size_t)((bq + bi) * TT + t)) * 2048 + (size_t)dir * 1024;
            xgi[bi] = xg[xa + j];
            xgf[bi] = xg[xa + 256 + j];
            xgg[bi] = xg[xa + 512 + j];
            xgo[bi] = xg[xa + 768 + j];
        }
        f32x4 acc[4];
#pragma unroll
        for (int m = 0; m < 4; ++m) acc[m] = (f32x4){0.f, 0.f, 0.f, 0.f};
        // kt 0..3: register-resident
#pragma unroll
        for (int kt = 0; kt < 4; ++kt) {
            bf16x8 hfr = *(const bf16x8*)&h_bf[l15][kt * 32 + qq * 8];
#pragma unroll
            for (int m = 0; m < 4; ++m)
                acc[m] = __builtin_amdgcn_mfma_f32_16x16x32_bf16(wreg[m][kt], hfr, acc[m], 0, 0, 0);
        }
        // kt 4,5: LDS-resident
#pragma unroll
        for (int kk = 0; kk < 2; ++kk) {
            bf16x8 hfr = *(const bf16x8*)&h_bf[l15][(4 + kk) * 32 + qq * 8];
#pragma unroll
            for (int m = 0; m < 4; ++m) {
                bf16x8 ws = *(const bf16x8*)&wlds[kk][wid * 4 + m][lane * 8];
                acc[m] = __builtin_amdgcn_mfma_f32_16x16x32_bf16(ws, hfr, acc[m], 0, 0, 0);
            }
        }
        // kt 6,7: streamed from L2 (128 KB/step)
#pragma unroll
        for (int kt = 6; kt < 8; ++kt) {
            bf16x8 hfr = *(const bf16x8*)&h_bf[l15][kt * 32 + qq * 8];
#pragma unroll
            for (int m = 0; m < 4; ++m) {
                bf16x8 ws = *(const bf16x8*)(wbase + (size_t)(m * 8 + kt) * 512);
                acc[m] = __builtin_amdgcn_mfma_f32_16x16x32_bf16(ws, hfr, acc[m], 0, 0, 0);
            }
        }
        if (l15 < 8) {
#pragma unroll
            for (int m = 0; m < 4; ++m) {
                int R = (wid * 4 + m) * 16 + qq * 4;
#pragma unroll
                for (int jj = 0; jj < 4; ++jj) g_bf[R + jj][l15] = f2bf(acc[m][jj]);
            }
        }
        __syncthreads();
#pragma unroll
        for (int bi = 0; bi < 2; ++bi) {
            int b = bq + bi;
            float gi = xgi[bi] + bi_ + bf2f(g_bf[j][b]);
            float gf = xgf[bi] + bf_ + bf2f(g_bf[256 + j][b]);
            float gg = xgg[bi] + bg_ + bf2f(g_bf[512 + j][b]);
            float go = xgo[bi] + bo_ + bf2f(g_bf[768 + j][b]);
            float cc = sigmf(gf) * c_s[bi] + sigmf(gi) * tanhf(gg);
            c_s[bi] = cc;
            float hh = sigmf(go) * tanhf(cc);
            h_bf[b][j] = f2bf(hh);
            hout[((size_t)(b * TT + t)) * LH_ + j] = hh;
        }
        __syncthreads();
    }
}

// ---------------- classifier ----------------
__global__ __launch_bounds__(256) void clf_kernel(
    const float* __restrict__ hf, const float* __restrict__ hb,
    const float* __restrict__ W, const float* __restrict__ bias, float* __restrict__ em) {
    int idx = blockIdx.x * blockDim.x + threadIdx.x;
    if (idx >= BB * TT * KK_) return;
    int row = idx / KK_, j = idx % KK_;
    float acc = bias[j];
    const float* hfp = hf + (size_t)row * LH_;
    const float* hbp = hb + (size_t)row * LH_;
    for (int kk = 0; kk < LH_; ++kk) acc += hfp[kk] * W[kk * KK_ + j];
    for (int kk = 0; kk < LH_; ++kk) acc += hbp[kk] * W[(LH_ + kk) * KK_ + j];
    em[idx] = acc;
}

// ---------------- CRF ----------------
__global__ __launch_bounds__(128) void crf_kernel(
    const float* __restrict__ em, const int* __restrict__ labels, const int* __restrict__ mask,
    const float* __restrict__ cstart, const float* __restrict__ cend,
    const float* __restrict__ ctrans, float* __restrict__ out) {
    __shared__ float alpha[BB][KK_], nxt[BB][KK_], trans[KK_ * KK_];
    __shared__ float score_s[BB], logZ_s[BB];
    int tid = threadIdx.x;
    if (tid < KK_ * KK_) trans[tid] = ctrans[tid];
    __syncthreads();
    int b = tid / KK_, j = tid % KK_;
    if (tid < BB * KK_) alpha[b][j] = cstart[j] + em[(size_t)b * TT * KK_ + j];
    __syncthreads();
    for (int t = 1; t < TT; ++t) {
        if (tid < BB * KK_) {
            float m = -1e30f;
            for (int i = 0; i < KK_; ++i) m = fmaxf(m, alpha[b][i] + trans[i * KK_ + j]);
            float s = 0.f;
            for (int i = 0; i < KK_; ++i) s += expf(alpha[b][i] + trans[i * KK_ + j] - m);
            float nv = m + logf(s) + em[((size_t)b * TT + t) * KK_ + j];
            nxt[b][j] = (mask[b * TT + t] > 0) ? nv : alpha[b][j];
        }
        __syncthreads();
        if (tid < BB * KK_) alpha[b][j] = nxt[b][j];
        __syncthreads();
    }
    if (tid < BB) {
        int bb = tid;
        int l0 = labels[bb * TT];
        float sc = cstart[l0] + em[(size_t)bb * TT * KK_ + l0];
        int prev = l0;
        for (int t = 1; t < TT; ++t) {
            int lt = labels[bb * TT + t];
            float mf = (float)mask[bb * TT + t];
            sc += (trans[prev * KK_ + lt] + em[((size_t)bb * TT + t) * KK_ + lt]) * mf;
            prev = lt;
        }
        int ends = 0;
        for (int t = 0; t < TT; ++t) ends += mask[bb * TT + t];
        ends -= 1;
        int last = labels[bb * TT + ends];
        sc += cend[last];
        score_s[bb] = sc;
        float m = -1e30f;
        for (int jj = 0; jj < KK_; ++jj) m = fmaxf(m, alpha[bb][jj] + cend[jj]);
        float s = 0.f;
        for (int jj = 0; jj < KK_; ++jj) s += expf(alpha[bb][jj] + cend[jj] - m);
        logZ_s[bb] = m + logf(s);
    }
    __syncthreads();
    if (tid == 0) {
        float acc = 0.f;
        for (int bb = 0; bb < BB; ++bb) acc += score_s[bb] - logZ_s[bb];
        out[0] = -acc / (float)BB;
    }
}

extern "C" void kernel_launch(void* const* d_in, const int* in_sizes, int n_in,
                              void* d_out, int out_size, void* d_ws, size_t ws_size,
                              hipStream_t stream) {
    const int* input_ids = (const int*)d_in[0];
    const int* attn_mask = (const int*)d_in[1];
    const int* labels    = (const int*)d_in[2];
    const float* word_emb = (const float*)d_in[3];
    const float* pos_emb  = (const float*)d_in[4];
    const float* type_emb = (const float*)d_in[5];
    const float* emb_ln_g = (const float*)d_in[6];
    const float* emb_ln_b = (const float*)d_in[7];
    const float* Wq = (const float*)d_in[8];
    const float* bq = (const float*)d_in[9];
    const float* Wk = (const float*)d_in[10];
    const float* bk = (const float*)d_in[11];
    const float* Wv = (const float*)d_in[12];
    const float* bv = (const float*)d_in[13];
    const float* Wo = (const float*)d_in[14];
    const float* bo = (const float*)d_in[15];
    const float* ln1_g = (const float*)d_in[16];
    const float* ln1_b = (const float*)d_in[17];
    const float* Wf1 = (const float*)d_in[18];
    const float* bf1 = (const float*)d_in[19];
    const float* Wf2 = (const float*)d_in[20];
    const float* bf2 = (const float*)d_in[21];
    const float* ln2_g = (const float*)d_in[22];
    const float* ln2_b = (const float*)d_in[23];
    const float* w_ih_f = (const float*)d_in[24];
    const float* w_hh_f = (const float*)d_in[25];
    const float* b_ih_f = (const float*)d_in[26];
    const float* b_hh_f = (const float*)d_in[27];
    const float* w_ih_b = (const float*)d_in[28];
    const float* w_hh_b = (const float*)d_in[29];
    const float* b_ih_b = (const float*)d_in[30];
    const float* b_hh_b = (const float*)d_in[31];
    const float* W_clf  = (const float*)d_in[32];
    const float* b_clf  = (const float*)d_in[33];
    const float* crf_start = (const float*)d_in[34];
    const float* crf_end   = (const float*)d_in[35];
    const float* crf_trans = (const float*)d_in[36];

    const size_t NTOK = (size_t)BB * TT;          // 2048
    const size_t SZ = NTOK * HH;                  // 1,572,864

    float* ws = (float*)d_ws;
    float* x    = ws;                              // SZ
    float* qkv  = x + SZ;                          // 2048*2304
    float* tmp  = qkv + NTOK * 2304;               // SZ
    float* ab   = tmp + SZ;                        // SZ
    float* xg   = ab + SZ;                         // 2048*2048
    u16* x_bf   = (u16*)(xg + NTOK * 2048);        // SZ u16
    u16* ab_bf  = x_bf + SZ;
    u16* ctx_bf = ab_bf + SZ;
    u16* big_bf = ctx_bf + SZ;                     // 2048*3072
    u16* wbuf   = big_bf + NTOK * (size_t)FF_;     // 7,077,888
    u16* wihT   = wbuf + 7077888;                  // 2048*768
    u16* wfrag  = wihT + 1572864;                  // 524,288
    float* hf = qkv;
    float* hb = qkv + 524288;
    float* em = qkv + 1048576;

    embed_ln_kernel<<<NTOK, 256, 0, stream>>>(input_ids, word_emb, pos_emb, type_emb,
                                              emb_ln_g, emb_ln_b, x, x_bf);

    prep_kernel<<<1792, 256, 0, stream>>>(w_hh_f, w_hh_b, w_ih_f, w_ih_b, wfrag, wihT);

    dim3 gQKV(2304 / 128, NTOK / 128);  // 18 x 16
    dim3 gH(HH / 64, NTOK / 128);       // 12 x 16
    dim3 gF1(FF_ / 128, NTOK / 128);    // 24 x 16
    dim3 gG(2048 / 128, NTOK / 128);    // 16 x 16

    for (int l = 0; l < NL; ++l) {
        conv_layer_w2_kernel<<<1728, 256, 0, stream>>>(
            Wq + (size_t)l * HH * HH, Wk + (size_t)l * HH * HH,
            Wv + (size_t)l * HH * HH, Wo + (size_t)l * HH * HH,
            Wf1 + (size_t)l * HH * FF_, Wf2 + (size_t)l * FF_ * HH, wbuf);

        const float* bq_l = bq + (size_t)l * HH;
        const float* bk_l = bk + (size_t)l * HH;
        const float* bv_l = bv + (size_t)l * HH;
        const float* bo_l = bo + (size_t)l * HH;
        const float* g1 = ln1_g + (size_t)l * HH;
        const float* b1 = ln1_b + (size_t)l * HH;
        const float* bf1_l = bf1 + (size_t)l * FF_;
        const float* bf2_l = bf2 + (size_t)l * HH;
        const float* g2 = ln2_g + (size_t)l * HH;
        const float* b2 = ln2_b + (size_t)l * HH;

        gemm2_kernel<128, false, false><<<gQKV, 256, 0, stream>>>(
            x_bf, wbuf, bq_l, bk_l, bv_l, 768, qkv, nullptr, NTOK, 2304, HH);
        attention_kernel<<<BB * NH_ * 2, 256, 0, stream>>>(qkv, attn_mask, ctx_bf);
        gemm2_kernel<64, false, false><<<gH, 256, 0, stream>>>(
            ctx_bf, wbuf + 1769472, bo_l, bo_l, bo_l, 768, tmp, nullptr, NTOK, HH, HH);
        ln_residual_kernel<<<NTOK, 256, 0, stream>>>(x, tmp, g1, b1, ab, ab_bf);
        gemm2_kernel<128, true, true><<<gF1, 256, 0, stream>>>(
            ab_bf, wbuf + 2359296, bf1_l, bf1_l, bf1_l, FF_, nullptr, big_bf, NTOK, FF_, HH);
        gemm2_kernel<64, false, false><<<gH, 256, 0, stream>>>(
            big_bf, wbuf + 4718592, bf2_l, bf2_l, bf2_l, 768, tmp, nullptr, NTOK, HH, FF_);
        ln_residual_kernel<<<NTOK, 256, 0, stream>>>(ab, tmp, g2, b2, x, x_bf);
    }

    // fused LSTM input projections: xg[tok][dir*1024+g]
    gemm2_kernel<128, false, false><<<gG, 256, 0, stream>>>(
        x_bf, wihT, b_ih_f, b_ih_b, b_ih_b, 1024, xg, nullptr, NTOK, 2048, HH);

    lstm10_kernel<<<2, 1024, 0, stream>>>(xg, wfrag, b_hh_f, b_hh_b, hf, hb);
    clf_kernel<<<(BB * TT * KK_ + 255) / 256, 256, 0, stream>>>(hf, hb, W_clf, b_clf, em);
    crf_kernel<<<1, 128, 0, stream>>>(em, labels, attn_mask, crf_start, crf_end, crf_trans,
                                      (float*)d_out);
}

// Round 11
// 6166.502 us; speedup vs baseline: 1.0879x; 1.0071x over previous
//
#include <hip/hip_runtime.h>
#include <math.h>

#define BB 8
#define TT 256
#define HH 768
#define NL 12
#define NH_ 12
#define DH_ 64
#define FF_ 3072
#define LH_ 256
#define KK_ 9

typedef unsigned char u8;
typedef unsigned short u16;
typedef unsigned int u32;
typedef __attribute__((ext_vector_type(8))) short bf16x8;
typedef __attribute__((ext_vector_type(4))) float f32x4;

static __device__ __forceinline__ float sigmf(float x) { return 1.0f / (1.0f + expf(-x)); }

static __device__ __forceinline__ u16 f2bf(float f) {
    u32 u = __float_as_uint(f);
    u += 0x7fffu + ((u >> 16) & 1u);
    return (u16)(u >> 16);
}
static __device__ __forceinline__ float bf2f(u16 v) {
    return __uint_as_float(((u32)v) << 16);
}

// float -> OCP e4m3fn, RNE
static __device__ __forceinline__ u8 f2e4m3(float x) {
    float a = fabsf(x);
    u8 s = (u8)((__float_as_uint(x) >> 31) << 7);
    if (!(a > 0.001953125f)) {               // <= 2^-9
        int m = (int)rintf(a * 512.0f);      // 0 or 1
        return s | (u8)m;
    }
    if (a >= 448.0f) return s | 0x7E;
    int e; float fr = frexpf(a, &e);         // a = fr*2^e, fr in [0.5,1)
    int E = e - 1;
    if (E < -6) {                            // subnormal, step 2^-9
        int m = (int)rintf(a * 512.0f);      // 1..8
        if (m >= 8) return s | 0x08;
        return s | (u8)m;
    }
    int m = (int)rintf((fr * 2.0f - 1.0f) * 8.0f);   // 0..8
    if (m == 8) { E += 1; m = 0; if (E > 8) return s | 0x7E; }
    return s | (u8)((E + 7) << 3) | (u8)m;
}

static __device__ __forceinline__ f32x4 mfma_fp8(long a, long b, f32x4 c) {
    return __builtin_amdgcn_mfma_f32_16x16x32_fp8_fp8(a, b, c, 0, 0, 0);
}

#define GLL16(gp, lp) __builtin_amdgcn_global_load_lds( \
    (const __attribute__((address_space(1))) void*)(gp), \
    (__attribute__((address_space(3))) void*)(lp), 16, 0, 0)

// ---------------- block reduce ----------------
static __device__ __forceinline__ float block_sum(float v, float* red) {
    int tid = threadIdx.x;
#pragma unroll
    for (int o = 32; o > 0; o >>= 1) v += __shfl_xor(v, o);
    if ((tid & 63) == 0) red[tid >> 6] = v;
    __syncthreads();
    return red[0] + red[1] + red[2] + red[3];
}

// ---------------- embedding + LN ----------------
__global__ __launch_bounds__(256) void embed_ln_kernel(
    const int* __restrict__ ids, const float* __restrict__ we, const float* __restrict__ pe,
    const float* __restrict__ te, const float* __restrict__ g, const float* __restrict__ b,
    float* __restrict__ out, u16* __restrict__ outb) {
    int row = blockIdx.x;
    int t = row % TT;
    int id = ids[row];
    __shared__ float xr[HH];
    __shared__ float reda[8], redb[8];
    int tid = threadIdx.x;
    float s = 0.f;
    for (int h = tid; h < HH; h += 256) {
        float v = we[(size_t)id * HH + h] + pe[(size_t)t * HH + h] + te[h];
        xr[h] = v; s += v;
    }
    float mean = block_sum(s, reda) * (1.0f / HH);
    float vs = 0.f;
    for (int h = tid; h < HH; h += 256) { float d = xr[h] - mean; vs += d * d; }
    float var = block_sum(vs, redb) * (1.0f / HH);
    float rstd = rsqrtf(var + 1e-12f);
    for (int h = tid; h < HH; h += 256) {
        float v = (xr[h] - mean) * rstd * g[h] + b[h];
        out[(size_t)row * HH + h] = v;
        outb[(size_t)row * HH + h] = f2bf(v);
    }
}

// ---------------- LN(a + f) -> fp32 + bf16 ----------------
__global__ __launch_bounds__(256) void ln_residual_kernel(
    const float* __restrict__ a, const float* __restrict__ f,
    const float* __restrict__ g, const float* __restrict__ b,
    float* __restrict__ out, u16* __restrict__ outb) {
    int row = blockIdx.x;
    __shared__ float xr[HH];
    __shared__ float reda[8], redb[8];
    int tid = threadIdx.x;
    float s = 0.f;
    for (int h = tid; h < HH; h += 256) {
        float v = a[(size_t)row * HH + h] + f[(size_t)row * HH + h];
        xr[h] = v; s += v;
    }
    float mean = block_sum(s, reda) * (1.0f / HH);
    float vs = 0.f;
    for (int h = tid; h < HH; h += 256) { float d = xr[h] - mean; vs += d * d; }
    float var = block_sum(vs, redb) * (1.0f / HH);
    float rstd = rsqrtf(var + 1e-12f);
    for (int h = tid; h < HH; h += 256) {
        float v = (xr[h] - mean) * rstd * g[h] + b[h];
        out[(size_t)row * HH + h] = v;
        outb[(size_t)row * HH + h] = f2bf(v);
    }
}

// ---------------- per-layer weight transpose+convert v2: 64x64 tiles ----------------
__global__ __launch_bounds__(256) void conv_layer_w2_kernel(
    const float* __restrict__ Wq, const float* __restrict__ Wk,
    const float* __restrict__ Wv, const float* __restrict__ Wo,
    const float* __restrict__ Wf1, const float* __restrict__ Wf2,
    u16* __restrict__ wbuf) {
    __shared__ float tile[64][65];
    int bid = blockIdx.x;
    const float* src; u16* dst; int R, C, bx, by;
    if (bid < 576) {
        int m = bid / 144, t = bid % 144;
        src = (m == 0 ? Wq : m == 1 ? Wk : m == 2 ? Wv : Wo);
        dst = wbuf + (size_t)m * 589824;
        R = 768; C = 768; bx = t % 12; by = t / 12;
    } else if (bid < 1152) {
        int t = bid - 576;
        src = Wf1; dst = wbuf + 2359296; R = 768; C = 3072;
        bx = t % 48; by = t / 48;
    } else {
        int t = bid - 1152;
        src = Wf2; dst = wbuf + 4718592; R = 3072; C = 768;
        bx = t % 12; by = t / 12;
    }
    int tx = threadIdx.x & 15, ty = threadIdx.x >> 4;   // 16 x 16
#pragma unroll
    for (int p = 0; p < 4; ++p) {
        int row = p * 16 + ty;
        float4 v = *(const float4*)&src[(size_t)(by * 64 + row) * C + bx * 64 + tx * 4];
        tile[row][tx * 4 + 0] = v.x; tile[row][tx * 4 + 1] = v.y;
        tile[row][tx * 4 + 2] = v.z; tile[row][tx * 4 + 3] = v.w;
    }
    __syncthreads();
    int rr = (threadIdx.x & 31) * 2, cc0 = threadIdx.x >> 5;   // 8 cols/pass
#pragma unroll
    for (int p = 0; p < 8; ++p) {
        int cc = p * 8 + cc0;
        u32 pk = (u32)f2bf(tile[rr][cc]) | ((u32)f2bf(tile[rr + 1][cc]) << 16);
        *(u32*)&dst[(size_t)(bx * 64 + cc) * R + by * 64 + rr] = pk;
    }
}

// ---------------- merged prologue: pack w_hh fp8 frags (kt-major) + convert w_ih ----------------
__global__ __launch_bounds__(256) void prep_kernel(
    const float* __restrict__ whf, const float* __restrict__ whb,
    const float* __restrict__ wif, const float* __restrict__ wib,
    u8* __restrict__ wfrag8, u16* __restrict__ wihT) {
    int bid = blockIdx.x;
    int tid = threadIdx.x;
    if (bid < 256) {
        int idx = bid * 256 + tid;        // 65536 fragment-lanes
        int dir = idx >> 15;
        int kt  = (idx >> 12) & 7;
        int mt  = (idx >> 6) & 63;
        int lane = idx & 63;
        const float* W = dir ? whb : whf;
        int row = mt * 16 + (lane & 15);
        int k = kt * 32 + (lane >> 4) * 8;
        const float* src = W + (size_t)row * LH_ + k;
        u8 o[8];
#pragma unroll
        for (int j = 0; j < 8; ++j) o[j] = f2e4m3(src[j]);
        uint2 pk;
        pk.x = (u32)o[0] | ((u32)o[1] << 8) | ((u32)o[2] << 16) | ((u32)o[3] << 24);
        pk.y = (u32)o[4] | ((u32)o[5] << 8) | ((u32)o[6] << 16) | ((u32)o[7] << 24);
        size_t base = (size_t)(((dir * 8 + kt) * 64 + mt) * 64 + lane) * 8;
        *(uint2*)&wfrag8[base] = pk;
    } else {
        int which = (bid < 1024) ? 0 : 1;
        const float* src = which ? wib : wif;
        u16* dst = wihT + (size_t)which * 786432;
        int i = (bid - (which ? 1024 : 256)) * 256 + tid;   // < 196608
        float4 v = *(const float4*)&src[(size_t)i * 4];
        uint2 o;
        o.x = (u32)f2bf(v.x) | ((u32)f2bf(v.y) << 16);
        o.y = (u32)f2bf(v.z) | ((u32)f2bf(v.w) << 16);
        *(uint2*)&dst[(size_t)i * 4] = o;
    }
}

// ---------------- GEMM v2: swizzled LDS + 2-phase double buffer ----------------
template <int BROWS>
__device__ __forceinline__ void stage_rows(
    const u16* __restrict__ S, int r0, int K, int k0, u16 (*lds)[64], int w, int lane) {
    int srow = lane >> 3;
    int sgrp = ((lane & 7) ^ srow) * 8;
#pragma unroll
    for (int i = 0; i < BROWS / 32; ++i) {
        int c = w * (BROWS / 32) + i;
        GLL16(S + (size_t)(r0 + 8 * c + srow) * K + k0 + sgrp, &lds[8 * c][0]);
    }
}

template <int BN, bool GELU, bool OUTBF>
__global__ __launch_bounds__(256) void gemm2_kernel(
    const u16* __restrict__ A, const u16* __restrict__ BT,
    const float* __restrict__ b0, const float* __restrict__ b1, const float* __restrict__ b2,
    int seg, float* __restrict__ C, u16* __restrict__ Cbf, int M, int N, int K) {
    __shared__ u16 Als[2][128][64];
    __shared__ u16 Bls[2][BN][64];
    int tid = threadIdx.x, lane = tid & 63, w = tid >> 6;
    int m0 = blockIdx.y * 128, n0 = blockIdx.x * BN;
    int wr = w >> 1, wc = w & 1;
    int l15 = lane & 15, q = lane >> 4;
    constexpr int NJ = BN / 32;

    f32x4 acc[4][NJ];
#pragma unroll
    for (int mi = 0; mi < 4; ++mi)
#pragma unroll
        for (int nj = 0; nj < NJ; ++nj) acc[mi][nj] = (f32x4){0.f, 0.f, 0.f, 0.f};

    stage_rows<128>(A, m0, K, 0, Als[0], w, lane);
    stage_rows<BN>(BT, n0, K, 0, Bls[0], w, lane);
    __syncthreads();
    int KT = K >> 6, cur = 0;
    for (int kt = 0; kt < KT; ++kt) {
        if (kt + 1 < KT) {
            stage_rows<128>(A, m0, K, (kt + 1) << 6, Als[cur ^ 1], w, lane);
            stage_rows<BN>(BT, n0, K, (kt + 1) << 6, Bls[cur ^ 1], w, lane);
        }
#pragma unroll
        for (int ks = 0; ks < 2; ++ks) {
            int g8 = (((ks * 4 + q) ^ (l15 & 7)) * 8);
            bf16x8 bfr[NJ];
#pragma unroll
            for (int nj = 0; nj < NJ; ++nj)
                bfr[nj] = *(const bf16x8*)&Bls[cur][wc * (BN / 2) + nj * 16 + l15][g8];
#pragma unroll
            for (int mi = 0; mi < 4; ++mi) {
                bf16x8 a = *(const bf16x8*)&Als[cur][wr * 64 + mi * 16 + l15][g8];
#pragma unroll
                for (int nj = 0; nj < NJ; ++nj)
                    acc[mi][nj] = __builtin_amdgcn_mfma_f32_16x16x32_bf16(a, bfr[nj], acc[mi][nj], 0, 0, 0);
            }
        }
        __syncthreads();
        cur ^= 1;
    }

    int rbase = m0 + wr * 64 + q * 4;
    int cbase = n0 + wc * (BN / 2) + l15;
#pragma unroll
    for (int mi = 0; mi < 4; ++mi) {
#pragma unroll
        for (int nj = 0; nj < NJ; ++nj) {
            int col = cbase + nj * 16;
            int cc = col;
            const float* bp;
            if (cc < seg) bp = b0;
            else if (cc < 2 * seg) { bp = b1; cc -= seg; }
            else { bp = b2; cc -= 2 * seg; }
            float bias = bp[cc];
#pragma unroll
            for (int j = 0; j < 4; ++j) {
                int row = rbase + mi * 16 + j;
                float v = acc[mi][nj][j] + bias;
                if (GELU) v = 0.5f * v * (1.0f + erff(v * 0.70710678118654752f));
                if (OUTBF) Cbf[(size_t)row * N + col] = f2bf(v);
                else       C[(size_t)row * N + col] = v;
            }
        }
    }
}

// ---------------- attention v2: pair-lane split, no spill ----------------
__global__ __launch_bounds__(256) void attention_kernel(
    const float* __restrict__ qkv, const int* __restrict__ mask, u16* __restrict__ ctxb) {
    int bid = blockIdx.x;
    int half = bid & 1;
    int bh = bid >> 1;
    int b = bh / NH_, h = bh % NH_;
    int tid = threadIdx.x;
    int q_i = half * 128 + (tid >> 1);
    int dh = tid & 1;
    const float* qp = qkv + (size_t)(b * TT + q_i) * 2304 + h * DH_ + dh * 32;
    float qv[32];
#pragma unroll
    for (int d = 0; d < 8; ++d) {
        float4 v = *(const float4*)(qp + 4 * d);
        qv[4 * d] = v.x; qv[4 * d + 1] = v.y; qv[4 * d + 2] = v.z; qv[4 * d + 3] = v.w;
    }
    const float* kbase = qkv + (size_t)b * TT * 2304 + 768 + h * DH_ + dh * 32;
    const float* vbase = qkv + (size_t)b * TT * 2304 + 1536 + h * DH_ + dh * 32;
    __shared__ float bias_s[TT];
    for (int i = tid; i < TT; i += 256)
        bias_s[i] = (1.0f - (float)mask[b * TT + i]) * -10000.0f;
    __syncthreads();
    float acc[32] = {};
    float l = 0.f;
    for (int kk = 0; kk < TT; ++kk) {
        const float4* kp = (const float4*)(kbase + (size_t)kk * 2304);
        float4 s4 = {0.f, 0.f, 0.f, 0.f};
#pragma unroll
        for (int d = 0; d < 8; ++d) {
            float4 k4 = kp[d];
            s4.x += qv[4 * d] * k4.x;
            s4.y += qv[4 * d + 1] * k4.y;
            s4.z += qv[4 * d + 2] * k4.z;
            s4.w += qv[4 * d + 3] * k4.w;
        }
        float part = (s4.x + s4.y) + (s4.z + s4.w);
        float s = part + __shfl_xor(part, 1);
        s = s * 0.125f + bias_s[kk];
        float p = expf(s);
        l += p;
        const float4* vp = (const float4*)(vbase + (size_t)kk * 2304);
#pragma unroll
        for (int d = 0; d < 8; ++d) {
            float4 v4 = vp[d];
            acc[4 * d] += p * v4.x;
            acc[4 * d + 1] += p * v4.y;
            acc[4 * d + 2] += p * v4.z;
            acc[4 * d + 3] += p * v4.w;
        }
    }
    float inv = 1.0f / l;
    size_t base = (size_t)(b * TT + q_i) * HH + h * DH_ + dh * 32;
#pragma unroll
    for (int d = 0; d < 16; ++d) {
        u32 pk = (u32)f2bf(acc[2 * d] * inv) | ((u32)f2bf(acc[2 * d + 1] * inv) << 16);
        *(u32*)&ctxb[base + 2 * d] = pk;
    }
}

// ---------------- LSTM v11: fp8 weights — 4 k-slices LDS-resident, 4 streamed ----------------
// 2 blocks (dir), 1024 threads (16 waves). W fp8 = 256KB/dir; kt0-3 in LDS (128KB),
// kt4-7 streamed (128KB/step, half of bf16). h quantized to fp8 each step.
__global__ __launch_bounds__(1024, 4) void lstm11_kernel(
    const float* __restrict__ xg, const u8* __restrict__ wfrag8,
    const float* __restrict__ bhh_f, const float* __restrict__ bhh_b,
    float* __restrict__ hf, float* __restrict__ hb) {
    int dir = blockIdx.x;
    const u8* wf8 = wfrag8 + (size_t)dir * 262144;
    const float* bhh = dir ? bhh_b : bhh_f;
    float* hout = dir ? hb : hf;
    int tid = threadIdx.x, lane = tid & 63, wid = tid >> 6;   // wid 0..15
    __shared__ u8 wlds[4 * 64 * 512];     // kt 0..3: 128 KB
    __shared__ u8 h_f8[16][280];          // 4.375 KB (280 pad -> conflict-free)
    __shared__ u16 g_bf[1024][10];        // 20 KB
    for (int i = tid; i < 16 * 280; i += 1024) ((u8*)h_f8)[i] = 0;
    // stage kt 0..3 (128 KB contiguous, kt-major layout): 8 x 1KB chunks per wave
#pragma unroll
    for (int c = 0; c < 8; ++c) {
        int off = wid * 8192 + c * 1024;
        GLL16(wf8 + off + lane * 16, &wlds[off]);
    }
    int l15 = lane & 15, qq = lane >> 4;
    int j = tid & 255;
    int bq = (tid >> 8) * 2;   // 2 batches per thread
    float bi_ = bhh[j], bf_ = bhh[256 + j], bg_ = bhh[512 + j], bo_ = bhh[768 + j];
    float c_s[2] = {0.f, 0.f};
    __syncthreads();
    for (int step = 0; step < TT; ++step) {
        int t = dir ? (TT - 1 - step) : step;
        // prefetch streamed W (kt 4..7, this wave's 4 m-tiles): 16 x 8B
        long wst[4][4];
#pragma unroll
        for (int kt = 0; kt < 4; ++kt)
#pragma unroll
            for (int m = 0; m < 4; ++m)
                wst[kt][m] = *(const long*)&wf8[(size_t)(((4 + kt) * 64) + wid * 4 + m) * 512 + lane * 8];
        // prefetch xg
        float xgi[2], xgf[2], xgg[2], xgo[2];
#pragma unroll
        for (int bi = 0; bi < 2; ++bi) {
            size_t xa = ((size_t)((bq + bi) * TT + t)) * 2048 + (size_t)dir * 1024;
            xgi[bi] = xg[xa + j];
            xgf[bi] = xg[xa + 256 + j];
            xgg[bi] = xg[xa + 512 + j];
            xgo[bi] = xg[xa + 768 + j];
        }
        f32x4 acc[4];
#pragma unroll
        for (int m = 0; m < 4; ++m) acc[m] = (f32x4){0.f, 0.f, 0.f, 0.f};
        // kt 0..3: LDS-resident W
#pragma unroll
        for (int kt = 0; kt < 4; ++kt) {
            long hfr = *(const long*)&h_f8[l15][kt * 32 + qq * 8];
#pragma unroll
            for (int m = 0; m < 4; ++m) {
                long a = *(const long*)&wlds[(size_t)(kt * 64 + wid * 4 + m) * 512 + lane * 8];
                acc[m] = mfma_fp8(a, hfr, acc[m]);
            }
        }
        // kt 4..7: streamed
#pragma unroll
        for (int kt = 0; kt < 4; ++kt) {
            long hfr = *(const long*)&h_f8[l15][(4 + kt) * 32 + qq * 8];
#pragma unroll
            for (int m = 0; m < 4; ++m)
                acc[m] = mfma_fp8(wst[kt][m], hfr, acc[m]);
        }
        if (l15 < 8) {
#pragma unroll
            for (int m = 0; m < 4; ++m) {
                int R = (wid * 4 + m) * 16 + qq * 4;
#pragma unroll
                for (int jj = 0; jj < 4; ++jj) g_bf[R + jj][l15] = f2bf(acc[m][jj]);
            }
        }
        __syncthreads();
#pragma unroll
        for (int bi = 0; bi < 2; ++bi) {
            int b = bq + bi;
            float gi = xgi[bi] + bi_ + bf2f(g_bf[j][b]);
            float gf = xgf[bi] + bf_ + bf2f(g_bf[256 + j][b]);
            float gg = xgg[bi] + bg_ + bf2f(g_bf[512 + j][b]);
            float go = xgo[bi] + bo_ + bf2f(g_bf[768 + j][b]);
            float cc = sigmf(gf) * c_s[bi] + sigmf(gi) * tanhf(gg);
            c_s[bi] = cc;
            float hh = sigmf(go) * tanhf(cc);
            h_f8[b][j] = f2e4m3(hh);
            hout[((size_t)(b * TT + t)) * LH_ + j] = hh;
        }
        __syncthreads();
    }
}

// ---------------- classifier ----------------
__global__ __launch_bounds__(256) void clf_kernel(
    const float* __restrict__ hf, const float* __restrict__ hb,
    const float* __restrict__ W, const float* __restrict__ bias, float* __restrict__ em) {
    int idx = blockIdx.x * blockDim.x + threadIdx.x;
    if (idx >= BB * TT * KK_) return;
    int row = idx / KK_, j = idx % KK_;
    float acc = bias[j];
    const float* hfp = hf + (size_t)row * LH_;
    const float* hbp = hb + (size_t)row * LH_;
    for (int kk = 0; kk < LH_; ++kk) acc += hfp[kk] * W[kk * KK_ + j];
    for (int kk = 0; kk < LH_; ++kk) acc += hbp[kk] * W[(LH_ + kk) * KK_ + j];
    em[idx] = acc;
}

// ---------------- CRF v2: wave per batch, shfl-based alpha recursion ----------------
__global__ __launch_bounds__(512) void crf2_kernel(
    const float* __restrict__ em, const int* __restrict__ labels, const int* __restrict__ mask,
    const float* __restrict__ cstart, const float* __restrict__ cend,
    const float* __restrict__ ctrans, float* __restrict__ out) {
    __shared__ float trans_s[81];
    __shared__ float res[8];
    int tid = threadIdx.x;
    int b = tid >> 6;          // wave = batch
    int l = tid & 63;
    if (tid < 81) trans_s[tid] = ctrans[tid];
    __syncthreads();
    int lc = (l < 9) ? l : 0;
    float tcol[9];
#pragma unroll
    for (int i = 0; i < 9; ++i) tcol[i] = trans_s[i * 9 + lc];
    float alpha = (l < 9) ? cstart[lc] + em[(size_t)b * TT * KK_ + lc] : -1e30f;
    for (int t = 1; t < TT; ++t) {
        float e_t = (l < 9) ? em[((size_t)b * TT + t) * KK_ + lc] : 0.f;
        float m = -1e30f;
        float av[9];
#pragma unroll
        for (int i = 0; i < 9; ++i) {
            av[i] = __shfl(alpha, i) + tcol[i];
            m = fmaxf(m, av[i]);
        }
        float s = 0.f;
#pragma unroll
        for (int i = 0; i < 9; ++i) s += expf(av[i] - m);
        float nv = m + logf(s) + e_t;
        bool upd = (mask[b * TT + t] > 0) && (l < 9);
        alpha = upd ? nv : alpha;
    }
    // logZ
    float z = (l < 9) ? alpha + cend[lc] : -1e30f;
    float zm = z;
#pragma unroll
    for (int o = 32; o > 0; o >>= 1) zm = fmaxf(zm, __shfl_xor(zm, o));
    float zs = (l < 9) ? expf(z - zm) : 0.f;
#pragma unroll
    for (int o = 32; o > 0; o >>= 1) zs += __shfl_xor(zs, o);
    float logZ = zm + logf(zs);
    // gold score: parallel over t
    float sc = 0.f;
    int cnt = 0;
    for (int t = l; t < TT; t += 64) {
        cnt += mask[b * TT + t];
        if (t == 0) {
            int l0 = labels[b * TT];
            sc += cstart[l0] + em[(size_t)b * TT * KK_ + l0];
        } else {
            int lp = labels[b * TT + t - 1];
            int lt = labels[b * TT + t];
            sc += (trans_s[lp * KK_ + lt] + em[((size_t)b * TT + t) * KK_ + lt]) *
                  (float)mask[b * TT + t];
        }
    }
#pragma unroll
    for (int o = 32; o > 0; o >>= 1) { sc += __shfl_xor(sc, o); cnt += __shfl_xor(cnt, o); }
    if (l == 0) {
        int last = labels[b * TT + (cnt - 1)];
        sc += cend[last];
        res[b] = sc - logZ;
    }
    __syncthreads();
    if (tid == 0) {
        float acc = 0.f;
        for (int bb = 0; bb < BB; ++bb) acc += res[bb];
        out[0] = -acc / (float)BB;
    }
}

extern "C" void kernel_launch(void* const* d_in, const int* in_sizes, int n_in,
                              void* d_out, int out_size, void* d_ws, size_t ws_size,
                              hipStream_t stream) {
    const int* input_ids = (const int*)d_in[0];
    const int* attn_mask = (const int*)d_in[1];
    const int* labels    = (const int*)d_in[2];
    const float* word_emb = (const float*)d_in[3];
    const float* pos_emb  = (const float*)d_in[4];
    const float* type_emb = (const float*)d_in[5];
    const float* emb_ln_g = (const float*)d_in[6];
    const float* emb_ln_b = (const float*)d_in[7];
    const float* Wq = (const float*)d_in[8];
    const float* bq = (const float*)d_in[9];
    const float* Wk = (const float*)d_in[10];
    const float* bk = (const float*)d_in[11];
    const float* Wv = (const float*)d_in[12];
    const float* bv = (const float*)d_in[13];
    const float* Wo = (const float*)d_in[14];
    const float* bo = (const float*)d_in[15];
    const float* ln1_g = (const float*)d_in[16];
    const float* ln1_b = (const float*)d_in[17];
    const float* Wf1 = (const float*)d_in[18];
    const float* bf1 = (const float*)d_in[19];
    const float* Wf2 = (const float*)d_in[20];
    const float* bf2 = (const float*)d_in[21];
    const float* ln2_g = (const float*)d_in[22];
    const float* ln2_b = (const float*)d_in[23];
    const float* w_ih_f = (const float*)d_in[24];
    const float* w_hh_f = (const float*)d_in[25];
    const float* b_ih_f = (const float*)d_in[26];
    const float* b_hh_f = (const float*)d_in[27];
    const float* w_ih_b = (const float*)d_in[28];
    const float* w_hh_b = (const float*)d_in[29];
    const float* b_ih_b = (const float*)d_in[30];
    const float* b_hh_b = (const float*)d_in[31];
    const float* W_clf  = (const float*)d_in[32];
    const float* b_clf  = (const float*)d_in[33];
    const float* crf_start = (const float*)d_in[34];
    const float* crf_end   = (const float*)d_in[35];
    const float* crf_trans = (const float*)d_in[36];

    const size_t NTOK = (size_t)BB * TT;          // 2048
    const size_t SZ = NTOK * HH;                  // 1,572,864

    float* ws = (float*)d_ws;
    float* x    = ws;                              // SZ
    float* qkv  = x + SZ;                          // 2048*2304
    float* tmp  = qkv + NTOK * 2304;               // SZ
    float* ab   = tmp + SZ;                        // SZ
    float* xg   = ab + SZ;                         // 2048*2048
    u16* x_bf   = (u16*)(xg + NTOK * 2048);        // SZ u16
    u16* ab_bf  = x_bf + SZ;
    u16* ctx_bf = ab_bf + SZ;
    u16* big_bf = ctx_bf + SZ;                     // 2048*3072
    u16* wbuf   = big_bf + NTOK * (size_t)FF_;     // 7,077,888
    u16* wihT   = wbuf + 7077888;                  // 2048*768
    u8*  wfrag8 = (u8*)(wihT + 1572864);           // 524,288 bytes
    float* hf = qkv;
    float* hb = qkv + 524288;
    float* em = qkv + 1048576;

    embed_ln_kernel<<<NTOK, 256, 0, stream>>>(input_ids, word_emb, pos_emb, type_emb,
                                              emb_ln_g, emb_ln_b, x, x_bf);

    prep_kernel<<<1792, 256, 0, stream>>>(w_hh_f, w_hh_b, w_ih_f, w_ih_b, wfrag8, wihT);

    dim3 gQKV(2304 / 128, NTOK / 128);  // 18 x 16
    dim3 gH(HH / 64, NTOK / 128);       // 12 x 16
    dim3 gF1(FF_ / 128, NTOK / 128);    // 24 x 16
    dim3 gG(2048 / 128, NTOK / 128);    // 16 x 16

    for (int l = 0; l < NL; ++l) {
        conv_layer_w2_kernel<<<1728, 256, 0, stream>>>(
            Wq + (size_t)l * HH * HH, Wk + (size_t)l * HH * HH,
            Wv + (size_t)l * HH * HH, Wo + (size_t)l * HH * HH,
            Wf1 + (size_t)l * HH * FF_, Wf2 + (size_t)l * FF_ * HH, wbuf);

        const float* bq_l = bq + (size_t)l * HH;
        const float* bk_l = bk + (size_t)l * HH;
        const float* bv_l = bv + (size_t)l * HH;
        const float* bo_l = bo + (size_t)l * HH;
        const float* g1 = ln1_g + (size_t)l * HH;
        const float* b1 = ln1_b + (size_t)l * HH;
        const float* bf1_l = bf1 + (size_t)l * FF_;
        const float* bf2_l = bf2 + (size_t)l * HH;
        const float* g2 = ln2_g + (size_t)l * HH;
        const float* b2 = ln2_b + (size_t)l * HH;

        gemm2_kernel<128, false, false><<<gQKV, 256, 0, stream>>>(
            x_bf, wbuf, bq_l, bk_l, bv_l, 768, qkv, nullptr, NTOK, 2304, HH);
        attention_kernel<<<BB * NH_ * 2, 256, 0, stream>>>(qkv, attn_mask, ctx_bf);
        gemm2_kernel<64, false, false><<<gH, 256, 0, stream>>>(
            ctx_bf, wbuf + 1769472, bo_l, bo_l, bo_l, 768, tmp, nullptr, NTOK, HH, HH);
        ln_residual_kernel<<<NTOK, 256, 0, stream>>>(x, tmp, g1, b1, ab, ab_bf);
        gemm2_kernel<128, true, true><<<gF1, 256, 0, stream>>>(
            ab_bf, wbuf + 2359296, bf1_l, bf1_l, bf1_l, FF_, nullptr, big_bf, NTOK, FF_, HH);
        gemm2_kernel<64, false, false><<<gH, 256, 0, stream>>>(
            big_bf, wbuf + 4718592, bf2_l, bf2_l, bf2_l, 768, tmp, nullptr, NTOK, HH, FF_);
        ln_residual_kernel<<<NTOK, 256, 0, stream>>>(ab, tmp, g2, b2, x, x_bf);
    }

    // fused LSTM input projections: xg[tok][dir*1024+g]
    gemm2_kernel<128, false, false><<<gG, 256, 0, stream>>>(
        x_bf, wihT, b_ih_f, b_ih_b, b_ih_b, 1024, xg, nullptr, NTOK, 2048, HH);

    lstm11_kernel<<<2, 1024, 0, stream>>>(xg, wfrag8, b_hh_f, b_hh_b, hf, hb);
    clf_kernel<<<(BB * TT * KK_ + 255) / 256, 256, 0, stream>>>(hf, hb, W_clf, b_clf, em);
    crf2_kernel<<<1, 512, 0, stream>>>(em, labels, attn_mask, crf_start, crf_end, crf_trans,
                                       (float*)d_out);
}

// Round 12
// 5749.215 us; speedup vs baseline: 1.1669x; 1.0726x over previous
//
#include <hip/hip_runtime.h>
#include <math.h>

#define BB 8
#define TT 256
#define HH 768
#define NL 12
#define NH_ 12
#define DH_ 64
#define FF_ 3072
#define LH_ 256
#define KK_ 9

typedef unsigned char u8;
typedef unsigned short u16;
typedef unsigned int u32;
typedef __attribute__((ext_vector_type(8))) short bf16x8;
typedef __attribute__((ext_vector_type(4))) float f32x4;

static __device__ __forceinline__ float sigmf(float x) { return 1.0f / (1.0f + expf(-x)); }

// fast device transcendentals (v_exp/v_rcp)
static __device__ __forceinline__ float sigm_fast(float x) {
    return __builtin_amdgcn_rcpf(1.0f + __expf(-x));
}
static __device__ __forceinline__ float tanh_fast(float x) {
    return 1.0f - 2.0f * __builtin_amdgcn_rcpf(1.0f + __expf(2.0f * x));
}

static __device__ __forceinline__ u16 f2bf(float f) {
    u32 u = __float_as_uint(f);
    u += 0x7fffu + ((u >> 16) & 1u);
    return (u16)(u >> 16);
}
static __device__ __forceinline__ float bf2f(u16 v) {
    return __uint_as_float(((u32)v) << 16);
}

// float -> OCP e4m3fn, RNE (host-side prep path only)
static __device__ __forceinline__ u8 f2e4m3(float x) {
    float a = fabsf(x);
    u8 s = (u8)((__float_as_uint(x) >> 31) << 7);
    if (!(a > 0.001953125f)) {
        int m = (int)rintf(a * 512.0f);
        return s | (u8)m;
    }
    if (a >= 448.0f) return s | 0x7E;
    int e; float fr = frexpf(a, &e);
    int E = e - 1;
    if (E < -6) {
        int m = (int)rintf(a * 512.0f);
        if (m >= 8) return s | 0x08;
        return s | (u8)m;
    }
    int m = (int)rintf((fr * 2.0f - 1.0f) * 8.0f);
    if (m == 8) { E += 1; m = 0; if (E > 8) return s | 0x7E; }
    return s | (u8)((E + 7) << 3) | (u8)m;
}

static __device__ __forceinline__ f32x4 mfma_fp8(long a, long b, f32x4 c) {
    return __builtin_amdgcn_mfma_f32_16x16x32_fp8_fp8(a, b, c, 0, 0, 0);
}

#define GLL16(gp, lp) __builtin_amdgcn_global_load_lds( \
    (const __attribute__((address_space(1))) void*)(gp), \
    (__attribute__((address_space(3))) void*)(lp), 16, 0, 0)

// ---------------- block reduce ----------------
static __device__ __forceinline__ float block_sum(float v, float* red) {
    int tid = threadIdx.x;
#pragma unroll
    for (int o = 32; o > 0; o >>= 1) v += __shfl_xor(v, o);
    if ((tid & 63) == 0) red[tid >> 6] = v;
    __syncthreads();
    return red[0] + red[1] + red[2] + red[3];
}

// ---------------- embedding + LN ----------------
__global__ __launch_bounds__(256) void embed_ln_kernel(
    const int* __restrict__ ids, const float* __restrict__ we, const float* __restrict__ pe,
    const float* __restrict__ te, const float* __restrict__ g, const float* __restrict__ b,
    float* __restrict__ out, u16* __restrict__ outb) {
    int row = blockIdx.x;
    int t = row % TT;
    int id = ids[row];
    __shared__ float xr[HH];
    __shared__ float reda[8], redb[8];
    int tid = threadIdx.x;
    float s = 0.f;
    for (int h = tid; h < HH; h += 256) {
        float v = we[(size_t)id * HH + h] + pe[(size_t)t * HH + h] + te[h];
        xr[h] = v; s += v;
    }
    float mean = block_sum(s, reda) * (1.0f / HH);
    float vs = 0.f;
    for (int h = tid; h < HH; h += 256) { float d = xr[h] - mean; vs += d * d; }
    float var = block_sum(vs, redb) * (1.0f / HH);
    float rstd = rsqrtf(var + 1e-12f);
    for (int h = tid; h < HH; h += 256) {
        float v = (xr[h] - mean) * rstd * g[h] + b[h];
        out[(size_t)row * HH + h] = v;
        outb[(size_t)row * HH + h] = f2bf(v);
    }
}

// ---------------- LN(a + f) -> fp32 + bf16 ----------------
__global__ __launch_bounds__(256) void ln_residual_kernel(
    const float* __restrict__ a, const float* __restrict__ f,
    const float* __restrict__ g, const float* __restrict__ b,
    float* __restrict__ out, u16* __restrict__ outb) {
    int row = blockIdx.x;
    __shared__ float xr[HH];
    __shared__ float reda[8], redb[8];
    int tid = threadIdx.x;
    float s = 0.f;
    for (int h = tid; h < HH; h += 256) {
        float v = a[(size_t)row * HH + h] + f[(size_t)row * HH + h];
        xr[h] = v; s += v;
    }
    float mean = block_sum(s, reda) * (1.0f / HH);
    float vs = 0.f;
    for (int h = tid; h < HH; h += 256) { float d = xr[h] - mean; vs += d * d; }
    float var = block_sum(vs, redb) * (1.0f / HH);
    float rstd = rsqrtf(var + 1e-12f);
    for (int h = tid; h < HH; h += 256) {
        float v = (xr[h] - mean) * rstd * g[h] + b[h];
        out[(size_t)row * HH + h] = v;
        outb[(size_t)row * HH + h] = f2bf(v);
    }
}

// ---------------- per-layer weight transpose+convert v2: 64x64 tiles ----------------
__global__ __launch_bounds__(256) void conv_layer_w2_kernel(
    const float* __restrict__ Wq, const float* __restrict__ Wk,
    const float* __restrict__ Wv, const float* __restrict__ Wo,
    const float* __restrict__ Wf1, const float* __restrict__ Wf2,
    u16* __restrict__ wbuf) {
    __shared__ float tile[64][65];
    int bid = blockIdx.x;
    const float* src; u16* dst; int R, C, bx, by;
    if (bid < 576) {
        int m = bid / 144, t = bid % 144;
        src = (m == 0 ? Wq : m == 1 ? Wk : m == 2 ? Wv : Wo);
        dst = wbuf + (size_t)m * 589824;
        R = 768; C = 768; bx = t % 12; by = t / 12;
    } else if (bid < 1152) {
        int t = bid - 576;
        src = Wf1; dst = wbuf + 2359296; R = 768; C = 3072;
        bx = t % 48; by = t / 48;
    } else {
        int t = bid - 1152;
        src = Wf2; dst = wbuf + 4718592; R = 3072; C = 768;
        bx = t % 12; by = t / 12;
    }
    int tx = threadIdx.x & 15, ty = threadIdx.x >> 4;   // 16 x 16
#pragma unroll
    for (int p = 0; p < 4; ++p) {
        int row = p * 16 + ty;
        float4 v = *(const float4*)&src[(size_t)(by * 64 + row) * C + bx * 64 + tx * 4];
        tile[row][tx * 4 + 0] = v.x; tile[row][tx * 4 + 1] = v.y;
        tile[row][tx * 4 + 2] = v.z; tile[row][tx * 4 + 3] = v.w;
    }
    __syncthreads();
    int rr = (threadIdx.x & 31) * 2, cc0 = threadIdx.x >> 5;   // 8 cols/pass
#pragma unroll
    for (int p = 0; p < 8; ++p) {
        int cc = p * 8 + cc0;
        u32 pk = (u32)f2bf(tile[rr][cc]) | ((u32)f2bf(tile[rr + 1][cc]) << 16);
        *(u32*)&dst[(size_t)(bx * 64 + cc) * R + by * 64 + rr] = pk;
    }
}

// ---------------- merged prologue: pack w_hh fp8 frags (kt-major) + convert w_ih ----------------
__global__ __launch_bounds__(256) void prep_kernel(
    const float* __restrict__ whf, const float* __restrict__ whb,
    const float* __restrict__ wif, const float* __restrict__ wib,
    u8* __restrict__ wfrag8, u16* __restrict__ wihT) {
    int bid = blockIdx.x;
    int tid = threadIdx.x;
    if (bid < 256) {
        int idx = bid * 256 + tid;        // 65536 fragment-lanes
        int dir = idx >> 15;
        int kt  = (idx >> 12) & 7;
        int mt  = (idx >> 6) & 63;
        int lane = idx & 63;
        const float* W = dir ? whb : whf;
        int row = mt * 16 + (lane & 15);
        int k = kt * 32 + (lane >> 4) * 8;
        const float* src = W + (size_t)row * LH_ + k;
        u8 o[8];
#pragma unroll
        for (int j = 0; j < 8; ++j) o[j] = f2e4m3(src[j]);
        uint2 pk;
        pk.x = (u32)o[0] | ((u32)o[1] << 8) | ((u32)o[2] << 16) | ((u32)o[3] << 24);
        pk.y = (u32)o[4] | ((u32)o[5] << 8) | ((u32)o[6] << 16) | ((u32)o[7] << 24);
        size_t base = (size_t)(((dir * 8 + kt) * 64 + mt) * 64 + lane) * 8;
        *(uint2*)&wfrag8[base] = pk;
    } else {
        int which = (bid < 1024) ? 0 : 1;
        const float* src = which ? wib : wif;
        u16* dst = wihT + (size_t)which * 786432;
        int i = (bid - (which ? 1024 : 256)) * 256 + tid;   // < 196608
        float4 v = *(const float4*)&src[(size_t)i * 4];
        uint2 o;
        o.x = (u32)f2bf(v.x) | ((u32)f2bf(v.y) << 16);
        o.y = (u32)f2bf(v.z) | ((u32)f2bf(v.w) << 16);
        *(uint2*)&dst[(size_t)i * 4] = o;
    }
}

// ---------------- GEMM v2: swizzled LDS + 2-phase double buffer ----------------
template <int BROWS>
__device__ __forceinline__ void stage_rows(
    const u16* __restrict__ S, int r0, int K, int k0, u16 (*lds)[64], int w, int lane) {
    int srow = lane >> 3;
    int sgrp = ((lane & 7) ^ srow) * 8;
#pragma unroll
    for (int i = 0; i < BROWS / 32; ++i) {
        int c = w * (BROWS / 32) + i;
        GLL16(S + (size_t)(r0 + 8 * c + srow) * K + k0 + sgrp, &lds[8 * c][0]);
    }
}

template <int BN, bool GELU, bool OUTBF>
__global__ __launch_bounds__(256) void gemm2_kernel(
    const u16* __restrict__ A, const u16* __restrict__ BT,
    const float* __restrict__ b0, const float* __restrict__ b1, const float* __restrict__ b2,
    int seg, float* __restrict__ C, u16* __restrict__ Cbf, int M, int N, int K) {
    __shared__ u16 Als[2][128][64];
    __shared__ u16 Bls[2][BN][64];
    int tid = threadIdx.x, lane = tid & 63, w = tid >> 6;
    int m0 = blockIdx.y * 128, n0 = blockIdx.x * BN;
    int wr = w >> 1, wc = w & 1;
    int l15 = lane & 15, q = lane >> 4;
    constexpr int NJ = BN / 32;

    f32x4 acc[4][NJ];
#pragma unroll
    for (int mi = 0; mi < 4; ++mi)
#pragma unroll
        for (int nj = 0; nj < NJ; ++nj) acc[mi][nj] = (f32x4){0.f, 0.f, 0.f, 0.f};

    stage_rows<128>(A, m0, K, 0, Als[0], w, lane);
    stage_rows<BN>(BT, n0, K, 0, Bls[0], w, lane);
    __syncthreads();
    int KT = K >> 6, cur = 0;
    for (int kt = 0; kt < KT; ++kt) {
        if (kt + 1 < KT) {
            stage_rows<128>(A, m0, K, (kt + 1) << 6, Als[cur ^ 1], w, lane);
            stage_rows<BN>(BT, n0, K, (kt + 1) << 6, Bls[cur ^ 1], w, lane);
        }
#pragma unroll
        for (int ks = 0; ks < 2; ++ks) {
            int g8 = (((ks * 4 + q) ^ (l15 & 7)) * 8);
            bf16x8 bfr[NJ];
#pragma unroll
            for (int nj = 0; nj < NJ; ++nj)
                bfr[nj] = *(const bf16x8*)&Bls[cur][wc * (BN / 2) + nj * 16 + l15][g8];
#pragma unroll
            for (int mi = 0; mi < 4; ++mi) {
                bf16x8 a = *(const bf16x8*)&Als[cur][wr * 64 + mi * 16 + l15][g8];
#pragma unroll
                for (int nj = 0; nj < NJ; ++nj)
                    acc[mi][nj] = __builtin_amdgcn_mfma_f32_16x16x32_bf16(a, bfr[nj], acc[mi][nj], 0, 0, 0);
            }
        }
        __syncthreads();
        cur ^= 1;
    }

    int rbase = m0 + wr * 64 + q * 4;
    int cbase = n0 + wc * (BN / 2) + l15;
#pragma unroll
    for (int mi = 0; mi < 4; ++mi) {
#pragma unroll
        for (int nj = 0; nj < NJ; ++nj) {
            int col = cbase + nj * 16;
            int cc = col;
            const float* bp;
            if (cc < seg) bp = b0;
            else if (cc < 2 * seg) { bp = b1; cc -= seg; }
            else { bp = b2; cc -= 2 * seg; }
            float bias = bp[cc];
#pragma unroll
            for (int j = 0; j < 4; ++j) {
                int row = rbase + mi * 16 + j;
                float v = acc[mi][nj][j] + bias;
                if (GELU) v = 0.5f * v * (1.0f + erff(v * 0.70710678118654752f));
                if (OUTBF) Cbf[(size_t)row * N + col] = f2bf(v);
                else       C[(size_t)row * N + col] = v;
            }
        }
    }
}

// ---------------- attention v2: pair-lane split, no spill ----------------
__global__ __launch_bounds__(256) void attention_kernel(
    const float* __restrict__ qkv, const int* __restrict__ mask, u16* __restrict__ ctxb) {
    int bid = blockIdx.x;
    int half = bid & 1;
    int bh = bid >> 1;
    int b = bh / NH_, h = bh % NH_;
    int tid = threadIdx.x;
    int q_i = half * 128 + (tid >> 1);
    int dh = tid & 1;
    const float* qp = qkv + (size_t)(b * TT + q_i) * 2304 + h * DH_ + dh * 32;
    float qv[32];
#pragma unroll
    for (int d = 0; d < 8; ++d) {
        float4 v = *(const float4*)(qp + 4 * d);
        qv[4 * d] = v.x; qv[4 * d + 1] = v.y; qv[4 * d + 2] = v.z; qv[4 * d + 3] = v.w;
    }
    const float* kbase = qkv + (size_t)b * TT * 2304 + 768 + h * DH_ + dh * 32;
    const float* vbase = qkv + (size_t)b * TT * 2304 + 1536 + h * DH_ + dh * 32;
    __shared__ float bias_s[TT];
    for (int i = tid; i < TT; i += 256)
        bias_s[i] = (1.0f - (float)mask[b * TT + i]) * -10000.0f;
    __syncthreads();
    float acc[32] = {};
    float l = 0.f;
    for (int kk = 0; kk < TT; ++kk) {
        const float4* kp = (const float4*)(kbase + (size_t)kk * 2304);
        float4 s4 = {0.f, 0.f, 0.f, 0.f};
#pragma unroll
        for (int d = 0; d < 8; ++d) {
            float4 k4 = kp[d];
            s4.x += qv[4 * d] * k4.x;
            s4.y += qv[4 * d + 1] * k4.y;
            s4.z += qv[4 * d + 2] * k4.z;
            s4.w += qv[4 * d + 3] * k4.w;
        }
        float part = (s4.x + s4.y) + (s4.z + s4.w);
        float s = part + __shfl_xor(part, 1);
        s = s * 0.125f + bias_s[kk];
        float p = expf(s);
        l += p;
        const float4* vp = (const float4*)(vbase + (size_t)kk * 2304);
#pragma unroll
        for (int d = 0; d < 8; ++d) {
            float4 v4 = vp[d];
            acc[4 * d] += p * v4.x;
            acc[4 * d + 1] += p * v4.y;
            acc[4 * d + 2] += p * v4.z;
            acc[4 * d + 3] += p * v4.w;
        }
    }
    float inv = 1.0f / l;
    size_t base = (size_t)(b * TT + q_i) * HH + h * DH_ + dh * 32;
#pragma unroll
    for (int d = 0; d < 16; ++d) {
        u32 pk = (u32)f2bf(acc[2 * d] * inv) | ((u32)f2bf(acc[2 * d + 1] * inv) << 16);
        *(u32*)&ctxb[base + 2 * d] = pk;
    }
}

// ---------------- LSTM v12: fp8 weights + fast-VALU update phase ----------------
// structure = lstm11 (kt0-3 LDS, kt4-7 streamed); update uses v_exp/v_rcp,
// hw fp8 convert (v_cvt_pk_fp8_f32), trunc-bf16 g writes.
__global__ __launch_bounds__(1024, 4) void lstm12_kernel(
    const float* __restrict__ xg, const u8* __restrict__ wfrag8,
    const float* __restrict__ bhh_f, const float* __restrict__ bhh_b,
    float* __restrict__ hf, float* __restrict__ hb) {
    int dir = blockIdx.x;
    const u8* wf8 = wfrag8 + (size_t)dir * 262144;
    const float* bhh = dir ? bhh_b : bhh_f;
    float* hout = dir ? hb : hf;
    int tid = threadIdx.x, lane = tid & 63, wid = tid >> 6;   // wid 0..15
    __shared__ u8 wlds[4 * 64 * 512];     // kt 0..3: 128 KB
    __shared__ u8 h_f8[16][280];          // 4.375 KB
    __shared__ u16 g_bf[1024][10];        // 20 KB
    for (int i = tid; i < 16 * 280; i += 1024) ((u8*)h_f8)[i] = 0;
#pragma unroll
    for (int c = 0; c < 8; ++c) {
        int off = wid * 8192 + c * 1024;
        GLL16(wf8 + off + lane * 16, &wlds[off]);
    }
    int l15 = lane & 15, qq = lane >> 4;
    int j = tid & 255;
    int bq = (tid >> 8) * 2;   // 2 batches per thread
    float bi_ = bhh[j], bf_ = bhh[256 + j], bg_ = bhh[512 + j], bo_ = bhh[768 + j];
    float c_s[2] = {0.f, 0.f};
    __syncthreads();
    for (int step = 0; step < TT; ++step) {
        int t = dir ? (TT - 1 - step) : step;
        long wst[4][4];
#pragma unroll
        for (int kt = 0; kt < 4; ++kt)
#pragma unroll
            for (int m = 0; m < 4; ++m)
                wst[kt][m] = *(const long*)&wf8[(size_t)(((4 + kt) * 64) + wid * 4 + m) * 512 + lane * 8];
        float xgi[2], xgf[2], xgg[2], xgo[2];
#pragma unroll
        for (int bi = 0; bi < 2; ++bi) {
            size_t xa = ((size_t)((bq + bi) * TT + t)) * 2048 + (size_t)dir * 1024;
            xgi[bi] = xg[xa + j];
            xgf[bi] = xg[xa + 256 + j];
            xgg[bi] = xg[xa + 512 + j];
            xgo[bi] = xg[xa + 768 + j];
        }
        f32x4 acc[4];
#pragma unroll
        for (int m = 0; m < 4; ++m) acc[m] = (f32x4){0.f, 0.f, 0.f, 0.f};
#pragma unroll
        for (int kt = 0; kt < 4; ++kt) {
            long hfr = *(const long*)&h_f8[l15][kt * 32 + qq * 8];
#pragma unroll
            for (int m = 0; m < 4; ++m) {
                long a = *(const long*)&wlds[(size_t)(kt * 64 + wid * 4 + m) * 512 + lane * 8];
                acc[m] = mfma_fp8(a, hfr, acc[m]);
            }
        }
#pragma unroll
        for (int kt = 0; kt < 4; ++kt) {
            long hfr = *(const long*)&h_f8[l15][(4 + kt) * 32 + qq * 8];
#pragma unroll
            for (int m = 0; m < 4; ++m)
                acc[m] = mfma_fp8(wst[kt][m], hfr, acc[m]);
        }
        if (l15 < 8) {
#pragma unroll
            for (int m = 0; m < 4; ++m) {
                int R = (wid * 4 + m) * 16 + qq * 4;
#pragma unroll
                for (int jj = 0; jj < 4; ++jj)
                    g_bf[R + jj][l15] = (u16)(__float_as_uint(acc[m][jj]) >> 16);  // trunc bf16
            }
        }
        __syncthreads();
#pragma unroll
        for (int bi = 0; bi < 2; ++bi) {
            int b = bq + bi;
            float gi = xgi[bi] + bi_ + bf2f(g_bf[j][b]);
            float gf = xgf[bi] + bf_ + bf2f(g_bf[256 + j][b]);
            float gg = xgg[bi] + bg_ + bf2f(g_bf[512 + j][b]);
            float go = xgo[bi] + bo_ + bf2f(g_bf[768 + j][b]);
            float cc = sigm_fast(gf) * c_s[bi] + sigm_fast(gi) * tanh_fast(gg);
            c_s[bi] = cc;
            float hh = sigm_fast(go) * tanh_fast(cc);
            int pk = __builtin_amdgcn_cvt_pk_fp8_f32(hh, hh, 0, false);
            h_f8[b][j] = (u8)(pk & 0xff);
            hout[((size_t)(b * TT + t)) * LH_ + j] = hh;
        }
        __syncthreads();
    }
}

// ---------------- classifier ----------------
__global__ __launch_bounds__(256) void clf_kernel(
    const float* __restrict__ hf, const float* __restrict__ hb,
    const float* __restrict__ W, const float* __restrict__ bias, float* __restrict__ em) {
    int idx = blockIdx.x * blockDim.x + threadIdx.x;
    if (idx >= BB * TT * KK_) return;
    int row = idx / KK_, j = idx % KK_;
    float acc = bias[j];
    const float* hfp = hf + (size_t)row * LH_;
    const float* hbp = hb + (size_t)row * LH_;
    for (int kk = 0; kk < LH_; ++kk) acc += hfp[kk] * W[kk * KK_ + j];
    for (int kk = 0; kk < LH_; ++kk) acc += hbp[kk] * W[(LH_ + kk) * KK_ + j];
    em[idx] = acc;
}

// ---------------- CRF v2: wave per batch, shfl-based alpha recursion ----------------
__global__ __launch_bounds__(512) void crf2_kernel(
    const float* __restrict__ em, const int* __restrict__ labels, const int* __restrict__ mask,
    const float* __restrict__ cstart, const float* __restrict__ cend,
    const float* __restrict__ ctrans, float* __restrict__ out) {
    __shared__ float trans_s[81];
    __shared__ float res[8];
    int tid = threadIdx.x;
    int b = tid >> 6;          // wave = batch
    int l = tid & 63;
    if (tid < 81) trans_s[tid] = ctrans[tid];
    __syncthreads();
    int lc = (l < 9) ? l : 0;
    float tcol[9];
#pragma unroll
    for (int i = 0; i < 9; ++i) tcol[i] = trans_s[i * 9 + lc];
    float alpha = (l < 9) ? cstart[lc] + em[(size_t)b * TT * KK_ + lc] : -1e30f;
    for (int t = 1; t < TT; ++t) {
        float e_t = (l < 9) ? em[((size_t)b * TT + t) * KK_ + lc] : 0.f;
        float m = -1e30f;
        float av[9];
#pragma unroll
        for (int i = 0; i < 9; ++i) {
            av[i] = __shfl(alpha, i) + tcol[i];
            m = fmaxf(m, av[i]);
        }
        float s = 0.f;
#pragma unroll
        for (int i = 0; i < 9; ++i) s += expf(av[i] - m);
        float nv = m + logf(s) + e_t;
        bool upd = (mask[b * TT + t] > 0) && (l < 9);
        alpha = upd ? nv : alpha;
    }
    float z = (l < 9) ? alpha + cend[lc] : -1e30f;
    float zm = z;
#pragma unroll
    for (int o = 32; o > 0; o >>= 1) zm = fmaxf(zm, __shfl_xor(zm, o));
    float zs = (l < 9) ? expf(z - zm) : 0.f;
#pragma unroll
    for (int o = 32; o > 0; o >>= 1) zs += __shfl_xor(zs, o);
    float logZ = zm + logf(zs);
    float sc = 0.f;
    int cnt = 0;
    for (int t = l; t < TT; t += 64) {
        cnt += mask[b * TT + t];
        if (t == 0) {
            int l0 = labels[b * TT];
            sc += cstart[l0] + em[(size_t)b * TT * KK_ + l0];
        } else {
            int lp = labels[b * TT + t - 1];
            int lt = labels[b * TT + t];
            sc += (trans_s[lp * KK_ + lt] + em[((size_t)b * TT + t) * KK_ + lt]) *
                  (float)mask[b * TT + t];
        }
    }
#pragma unroll
    for (int o = 32; o > 0; o >>= 1) { sc += __shfl_xor(sc, o); cnt += __shfl_xor(cnt, o); }
    if (l == 0) {
        int last = labels[b * TT + (cnt - 1)];
        sc += cend[last];
        res[b] = sc - logZ;
    }
    __syncthreads();
    if (tid == 0) {
        float acc = 0.f;
        for (int bb = 0; bb < BB; ++bb) acc += res[bb];
        out[0] = -acc / (float)BB;
    }
}

extern "C" void kernel_launch(void* const* d_in, const int* in_sizes, int n_in,
                              void* d_out, int out_size, void* d_ws, size_t ws_size,
                              hipStream_t stream) {
    const int* input_ids = (const int*)d_in[0];
    const int* attn_mask = (const int*)d_in[1];
    const int* labels    = (const int*)d_in[2];
    const float* word_emb = (const float*)d_in[3];
    const float* pos_emb  = (const float*)d_in[4];
    const float* type_emb = (const float*)d_in[5];
    const float* emb_ln_g = (const float*)d_in[6];
    const float* emb_ln_b = (const float*)d_in[7];
    const float* Wq = (const float*)d_in[8];
    const float* bq = (const float*)d_in[9];
    const float* Wk = (const float*)d_in[10];
    const float* bk = (const float*)d_in[11];
    const float* Wv = (const float*)d_in[12];
    const float* bv = (const float*)d_in[13];
    const float* Wo = (const float*)d_in[14];
    const float* bo = (const float*)d_in[15];
    const float* ln1_g = (const float*)d_in[16];
    const float* ln1_b = (const float*)d_in[17];
    const float* Wf1 = (const float*)d_in[18];
    const float* bf1 = (const float*)d_in[19];
    const float* Wf2 = (const float*)d_in[20];
    const float* bf2 = (const float*)d_in[21];
    const float* ln2_g = (const float*)d_in[22];
    const float* ln2_b = (const float*)d_in[23];
    const float* w_ih_f = (const float*)d_in[24];
    const float* w_hh_f = (const float*)d_in[25];
    const float* b_ih_f = (const float*)d_in[26];
    const float* b_hh_f = (const float*)d_in[27];
    const float* w_ih_b = (const float*)d_in[28];
    const float* w_hh_b = (const float*)d_in[29];
    const float* b_ih_b = (const float*)d_in[30];
    const float* b_hh_b = (const float*)d_in[31];
    const float* W_clf  = (const float*)d_in[32];
    const float* b_clf  = (const float*)d_in[33];
    const float* crf_start = (const float*)d_in[34];
    const float* crf_end   = (const float*)d_in[35];
    const float* crf_trans = (const float*)d_in[36];

    const size_t NTOK = (size_t)BB * TT;          // 2048
    const size_t SZ = NTOK * HH;                  // 1,572,864

    float* ws = (float*)d_ws;
    float* x    = ws;                              // SZ
    float* qkv  = x + SZ;                          // 2048*2304
    float* tmp  = qkv + NTOK * 2304;               // SZ
    float* ab   = tmp + SZ;                        // SZ
    float* xg   = ab + SZ;                         // 2048*2048
    u16* x_bf   = (u16*)(xg + NTOK * 2048);        // SZ u16
    u16* ab_bf  = x_bf + SZ;
    u16* ctx_bf = ab_bf + SZ;
    u16* big_bf = ctx_bf + SZ;                     // 2048*3072
    u16* wbuf   = big_bf + NTOK * (size_t)FF_;     // 7,077,888
    u16* wihT   = wbuf + 7077888;                  // 2048*768
    u8*  wfrag8 = (u8*)(wihT + 1572864);           // 524,288 bytes
    float* hf = qkv;
    float* hb = qkv + 524288;
    float* em = qkv + 1048576;

    embed_ln_kernel<<<NTOK, 256, 0, stream>>>(input_ids, word_emb, pos_emb, type_emb,
                                              emb_ln_g, emb_ln_b, x, x_bf);

    prep_kernel<<<1792, 256, 0, stream>>>(w_hh_f, w_hh_b, w_ih_f, w_ih_b, wfrag8, wihT);

    dim3 gQKV(2304 / 128, NTOK / 128);  // 18 x 16
    dim3 gH(HH / 64, NTOK / 128);       // 12 x 16
    dim3 gF1(FF_ / 128, NTOK / 128);    // 24 x 16
    dim3 gG(2048 / 128, NTOK / 128);    // 16 x 16

    for (int l = 0; l < NL; ++l) {
        conv_layer_w2_kernel<<<1728, 256, 0, stream>>>(
            Wq + (size_t)l * HH * HH, Wk + (size_t)l * HH * HH,
            Wv + (size_t)l * HH * HH, Wo + (size_t)l * HH * HH,
            Wf1 + (size_t)l * HH * FF_, Wf2 + (size_t)l * FF_ * HH, wbuf);

        const float* bq_l = bq + (size_t)l * HH;
        const float* bk_l = bk + (size_t)l * HH;
        const float* bv_l = bv + (size_t)l * HH;
        const float* bo_l = bo + (size_t)l * HH;
        const float* g1 = ln1_g + (size_t)l * HH;
        const float* b1 = ln1_b + (size_t)l * HH;
        const float* bf1_l = bf1 + (size_t)l * FF_;
        const float* bf2_l = bf2 + (size_t)l * HH;
        const float* g2 = ln2_g + (size_t)l * HH;
        const float* b2 = ln2_b + (size_t)l * HH;

        gemm2_kernel<128, false, false><<<gQKV, 256, 0, stream>>>(
            x_bf, wbuf, bq_l, bk_l, bv_l, 768, qkv, nullptr, NTOK, 2304, HH);
        attention_kernel<<<BB * NH_ * 2, 256, 0, stream>>>(qkv, attn_mask, ctx_bf);
        gemm2_kernel<64, false, false><<<gH, 256, 0, stream>>>(
            ctx_bf, wbuf + 1769472, bo_l, bo_l, bo_l, 768, tmp, nullptr, NTOK, HH, HH);
        ln_residual_kernel<<<NTOK, 256, 0, stream>>>(x, tmp, g1, b1, ab, ab_bf);
        gemm2_kernel<128, true, true><<<gF1, 256, 0, stream>>>(
            ab_bf, wbuf + 2359296, bf1_l, bf1_l, bf1_l, FF_, nullptr, big_bf, NTOK, FF_, HH);
        gemm2_kernel<64, false, false><<<gH, 256, 0, stream>>>(
            big_bf, wbuf + 4718592, bf2_l, bf2_l, bf2_l, 768, tmp, nullptr, NTOK, HH, FF_);
        ln_residual_kernel<<<NTOK, 256, 0, stream>>>(ab, tmp, g2, b2, x, x_bf);
    }

    // fused LSTM input projections: xg[tok][dir*1024+g]
    gemm2_kernel<128, false, false><<<gG, 256, 0, stream>>>(
        x_bf, wihT, b_ih_f, b_ih_b, b_ih_b, 1024, xg, nullptr, NTOK, 2048, HH);

    lstm12_kernel<<<2, 1024, 0, stream>>>(xg, wfrag8, b_hh_f, b_hh_b, hf, hb);
    clf_kernel<<<(BB * TT * KK_ + 255) / 256, 256, 0, stream>>>(hf, hb, W_clf, b_clf, em);
    crf2_kernel<<<1, 512, 0, stream>>>(em, labels, attn_mask, crf_start, crf_end, crf_trans,
                                       (float*)d_out);
}